// Round 1
// baseline (1318.773 us; speedup 1.0000x reference)
//
#include <hip/hip_runtime.h>
#include <hip/hip_bf16.h>

// LagLlama forward. fp32/bf16 input autodetect -> bf16 copies in ws.
// fp32 residual stream. Round 6 = R5 + causal skip/trunc in attention GEMMs,
// single-pass vectorized softmax, RoPE table, vectorized silu/rms/vtrans.
// B=2 T=1024 C=1024 NH=16 DH=64 L=4 HFF=2816

#define B_   2
#define T_   1024
#define C_   1024
#define NH_  16
#define DH_  64
#define L_   4
#define HFF_ 2816
#define EPS_ 1e-5f

typedef unsigned short u16;
typedef short bf16x8 __attribute__((ext_vector_type(8)));
typedef unsigned short u16x8 __attribute__((ext_vector_type(8)));
typedef float f32x4 __attribute__((ext_vector_type(4)));

__device__ __forceinline__ float b2f(u16 u) {
    union { unsigned int i; float f; } v; v.i = ((unsigned int)u) << 16; return v.f;
}
__device__ __forceinline__ u16 f2b(float f) {
    union { unsigned int i; float f; } v; v.f = f;
    unsigned int r = (v.i + 0x7fff + ((v.i >> 16) & 1)) >> 16;
    return (u16)r;
}

// flag: 0 = inputs are bf16, 1 = inputs are fp32 (detected from x's raw bits)
__global__ void detect_k(const unsigned int* __restrict__ xw, int* __restrict__ flag)
{
    int tid = threadIdx.x;
    int cnt = 0;
#pragma unroll
    for (int i = 0; i < 4; ++i) {
        unsigned int w = xw[tid * 4 + i];
        unsigned int e = (w >> 7) & 0xFF;
        if (e >= 0x70 && e <= 0x87) cnt++;
    }
#pragma unroll
    for (int off = 32; off; off >>= 1) cnt += __shfl_down(cnt, off);
    if (tid == 0) flag[0] = (cnt > 128) ? 0 : 1;
}

// Relayout+convert: for chunk y (blockIdx.y), vec4-index i:
//   dst4[y*dstStrideV + dstOffV + i] = cvt(src4[y*perV + i])
__global__ void cvt_k(const void* __restrict__ src, u16* __restrict__ dst,
                      long perV, long dstStrideV, long dstOffV,
                      const int* __restrict__ flag)
{
    const int f = flag[0];
    long y = blockIdx.y;
    long i = (long)blockIdx.x * 256 + threadIdx.x;
    long stride = (long)gridDim.x * 256;
    for (; i < perV; i += stride) {
        long so = y * perV + i;
        long dj = y * dstStrideV + dstOffV + i;
        ushort4 o;
        if (f) {
            float4 v = ((const float4*)src)[so];
            o.x = f2b(v.x); o.y = f2b(v.y); o.z = f2b(v.z); o.w = f2b(v.w);
        } else {
            o = ((const ushort4*)src)[so];
        }
        ((ushort4*)dst)[dj] = o;
    }
}

// ---------------------------------------------------------------------------
// Batched GEMM: C[m,n] = sum_k A[m,k] * B[n,k]   (A: MxK lda, B: NxK ldb)
// MODE 0: write bf16 to Cb; z = batch (bb=z/nhDiv, hh=z%nhDiv), offsets
//         bb*s?b + hh*s?h (elements). N per sub-gemm; tail via clamp+mask.
// MODE 1: z = K-slice (kSplit slices); atomicAdd fp32 into Cf.
// M % 128 == 0; K (or K/kSplit) % 32 == 0.
// flags bit0: causal block skip (skip if col0 > row0+127; downstream softmax
//             overwrites those positions with 0, so no write needed).
// flags bit1: causal K-truncation (A rows t only need k<=row0+127; A[k>t]==0).
// ---------------------------------------------------------------------------
template<int MODE>
__global__ __launch_bounds__(256, 2)
void gemm_bt(const u16* __restrict__ A, const u16* __restrict__ Bm,
             u16* __restrict__ Cb, float* __restrict__ Cf,
             int M, int N, int K, int lda, int ldb, int ldc,
             int nhDiv, long sAb, long sAh, long sBb, long sBh,
             long sCb, long sCh, int kSplit, int flags)
{
    __shared__ __align__(16) u16 tA[128 * 32];
    __shared__ __align__(16) u16 tB[128 * 32];

    const int z = blockIdx.z;
    int kBeg = 0, kEnd = K;
    const u16* Ab = A;
    const u16* Bb = Bm;
    long cOff = 0;
    if (MODE == 1) {
        int ks = K / kSplit;
        kBeg = z * ks; kEnd = kBeg + ks;
    } else {
        int bb = z / nhDiv;
        int hh = z - bb * nhDiv;
        Ab += bb * sAb + hh * sAh;
        Bb += bb * sBb + hh * sBh;
        cOff = bb * sCb + hh * sCh;
    }

    const int row0 = blockIdx.y * 128;
    const int col0 = blockIdx.x * 128;

    if ((flags & 1) && col0 > row0 + 127) return;   // fully-masked causal block
    if (flags & 2) { int ke = row0 + 128; if (ke < kEnd) kEnd = ke; }

    const int tid  = threadIdx.x;
    const int lane = tid & 63;
    const int wave = tid >> 6;
    const int wr = wave >> 1, wc = wave & 1;   // 2x2 waves of 64x64
    const int lrow = lane & 15;
    const int kg   = lane >> 4;

    f32x4 acc[4][4] = {};

    for (int k0 = kBeg; k0 < kEnd; k0 += 32) {
        __syncthreads();   // prior iter's LDS reads done before overwrite
#pragma unroll
        for (int i = 0; i < 2; ++i) {          // A tile: 512 x 16B chunks
            int chunk = i * 256 + tid;
            int r = chunk >> 2, cg = chunk & 3;
            const u16* ga = Ab + (long)(row0 + r) * lda + (k0 + cg * 8);
            u16* la = tA + (size_t)(i * 256 + wave * 64) * 8;  // wave-uniform
            __builtin_amdgcn_global_load_lds(
                (const __attribute__((address_space(1))) void*)ga,
                (__attribute__((address_space(3))) void*)la, 16, 0, 0);
        }
#pragma unroll
        for (int i = 0; i < 2; ++i) {          // B tile
            int chunk = i * 256 + tid;
            int r = chunk >> 2, cg = chunk & 3;
            int rB = col0 + r; if (rB > N - 1) rB = N - 1;   // N-tail clamp
            const u16* gb = Bb + (long)rB * ldb + (k0 + cg * 8);
            u16* lb = tB + (size_t)(i * 256 + wave * 64) * 8;
            __builtin_amdgcn_global_load_lds(
                (const __attribute__((address_space(1))) void*)gb,
                (__attribute__((address_space(3))) void*)lb, 16, 0, 0);
        }
        __syncthreads();

        bf16x8 af[4], bfr[4];
#pragma unroll
        for (int ti = 0; ti < 4; ++ti)
            af[ti] = *(const bf16x8*)&tA[(wr * 64 + ti * 16 + lrow) * 32 + kg * 8];
#pragma unroll
        for (int tj = 0; tj < 4; ++tj)
            bfr[tj] = *(const bf16x8*)&tB[(wc * 64 + tj * 16 + lrow) * 32 + kg * 8];
#pragma unroll
        for (int ti = 0; ti < 4; ++ti)
#pragma unroll
            for (int tj = 0; tj < 4; ++tj)
                acc[ti][tj] = __builtin_amdgcn_mfma_f32_16x16x32_bf16(
                    af[ti], bfr[tj], acc[ti][tj], 0, 0, 0);
    }

    // Epilogue: D[row = kg*4 + r][col = lane&15] per 16x16 tile.
    const int rbase = row0 + wr * 64;
    const int cbase = col0 + wc * 64 + lrow;
#pragma unroll
    for (int ti = 0; ti < 4; ++ti) {
#pragma unroll
        for (int r = 0; r < 4; ++r) {
            int row = rbase + ti * 16 + kg * 4 + r;
#pragma unroll
            for (int tj = 0; tj < 4; ++tj) {
                int col = cbase + tj * 16;
                if (col < N) {
                    long off = cOff + (long)row * ldc + col;
                    if (MODE == 0) Cb[off] = f2b(acc[ti][tj][r]);
                    else           atomicAdd(&Cf[off], acc[ti][tj][r]);
                }
            }
        }
    }
}

// h[bt,c] = sum_f x[bt,f] * w_in[c,f]   (K=9, fp32 out)
__global__ void input_proj_k(const u16* __restrict__ x, const u16* __restrict__ w,
                             float* __restrict__ h)
{
    int idx = blockIdx.x * 256 + threadIdx.x;      // 2M
    int bt = idx >> 10, c = idx & 1023;
    float s = 0.f;
#pragma unroll
    for (int f = 0; f < 9; ++f) s += b2f(x[bt * 9 + f]) * b2f(w[c * 9 + f]);
    h[idx] = s;
}

// out[row,:] = h * rsqrt(mean(h^2)+eps) * g.  isFinal&&flag -> fp32 out.
// Vectorized: 256 threads x float4 == C=1024 exactly.
__global__ void rms_k(const float* __restrict__ h, const u16* __restrict__ g,
                      void* __restrict__ out, int isFinal,
                      const int* __restrict__ flag)
{
    __shared__ float red[8];
    const int row = blockIdx.x;
    const int tid = threadIdx.x;
    float4 v = ((const float4*)(h + (size_t)row * C_))[tid];
    float ss = v.x * v.x + v.y * v.y + v.z * v.z + v.w * v.w;
#pragma unroll
    for (int off = 32; off; off >>= 1) ss += __shfl_down(ss, off);
    int lane = tid & 63, wave = tid >> 6;
    if (lane == 0) red[wave] = ss;
    __syncthreads();
    if (tid == 0)
        red[4] = rsqrtf((red[0] + red[1] + red[2] + red[3]) / (float)C_ + EPS_);
    __syncthreads();
    const float r = red[4];
    ushort4 gv = ((const ushort4*)g)[tid];
    float o0 = v.x * r * b2f(gv.x);
    float o1 = v.y * r * b2f(gv.y);
    float o2 = v.z * r * b2f(gv.z);
    float o3 = v.w * r * b2f(gv.w);
    if (isFinal && flag[0]) {
        ((float4*)out)[(size_t)row * 256 + tid] = make_float4(o0, o1, o2, o3);
    } else {
        ushort4 o; o.x = f2b(o0); o.y = f2b(o1); o.z = f2b(o2); o.w = f2b(o3);
        ((ushort4*)out)[(size_t)row * 256 + tid] = o;
    }
}

// cos/sin table: tab[t*32+i] = {cos,sin}(t * 10000^(-i/32)), t<1024, i<32
__global__ void rope_tab_k(float2* __restrict__ tab)
{
    int idx = blockIdx.x * 256 + threadIdx.x;      // 32768
    int i = idx & 31;
    int t = idx >> 5;
    float invf = powf(10000.0f, -(float)i / 32.0f);
    float fr = (float)t * invf;
    tab[idx] = make_float2(cosf(fr), sinf(fr));
}

// RoPE in place on qkv[b,t,:]: q cols 0..1023, k cols 1024..2047 (ld 3072)
__global__ void rope_k(u16* __restrict__ qkv, const float2* __restrict__ tab)
{
    int idx = blockIdx.x * 256 + threadIdx.x;      // B*T*NH*32 = 1M
    int i = idx & 31;
    int hh = (idx >> 5) & 15;
    int t = (idx >> 9) & 1023;
    int b = idx >> 19;
    float2 cs = tab[(t << 5) + i];
    float cf = cs.x, sf = cs.y;

    size_t base = (size_t)(b * 1024 + t) * 3072 + hh * 64 + i;
    float x1 = b2f(qkv[base]), x2 = b2f(qkv[base + 32]);
    qkv[base]      = f2b(x1 * cf - x2 * sf);
    qkv[base + 32] = f2b(x2 * cf + x1 * sf);

    size_t kb = base + 1024;
    x1 = b2f(qkv[kb]); x2 = b2f(qkv[kb + 32]);
    qkv[kb]      = f2b(x1 * cf - x2 * sf);
    qkv[kb + 32] = f2b(x2 * cf + x1 * sf);
}

// vt[b,h,d,s] = qkv[b,s, 2048 + h*64 + d]  — LDS-tiled 64x64 transpose,
// coalesced vector access on both global sides.
__global__ void vtrans_k(const u16* __restrict__ qkv, u16* __restrict__ vt)
{
    __shared__ u16 tile[64][68];                   // pad 4 u16
    const int bz = blockIdx.x;                     // 512 = 2b * 16h * 16s-tiles
    const int s0 = (bz & 15) << 6;
    const int hh = (bz >> 4) & 15;
    const int b  = bz >> 8;
    const int tid = threadIdx.x;
#pragma unroll
    for (int it = 0; it < 2; ++it) {
        int id = it * 256 + tid;                   // 0..511
        int r  = id >> 3;                          // s-row within tile
        int cg = id & 7;                           // 8-wide d chunk
        const u16* src = qkv + (size_t)(b * 1024 + s0 + r) * 3072
                             + 2048 + hh * 64 + cg * 8;
        ushort4 a0 = *(const ushort4*)src;
        ushort4 a1 = *(const ushort4*)(src + 4);
        *(ushort4*)&tile[r][cg * 8]     = a0;
        *(ushort4*)&tile[r][cg * 8 + 4] = a1;
    }
    __syncthreads();
#pragma unroll
    for (int it = 0; it < 2; ++it) {
        int id = it * 256 + tid;
        int d  = id >> 3;                          // d row of output
        int cg = id & 7;                           // 8-wide s chunk
        ushort4 o0, o1;
        o0.x = tile[cg * 8 + 0][d]; o0.y = tile[cg * 8 + 1][d];
        o0.z = tile[cg * 8 + 2][d]; o0.w = tile[cg * 8 + 3][d];
        o1.x = tile[cg * 8 + 4][d]; o1.y = tile[cg * 8 + 5][d];
        o1.z = tile[cg * 8 + 6][d]; o1.w = tile[cg * 8 + 7][d];
        u16* dst = vt + (size_t)((b * 16 + hh) * 64 + d) * 1024 + s0 + cg * 8;
        *(ushort4*)dst       = o0;
        *(ushort4*)(dst + 4) = o1;
    }
}

// Causal softmax row (z,t) in place; scale=0.125 folded in.
// Single pass: 256 threads x ushort4 = full 1024-wide row in registers.
// Masked lanes never consume memory contents (safe over skipped score blocks).
__global__ void softmax_k(u16* __restrict__ S)
{
    __shared__ float red[8];
    const int t = blockIdx.x & 1023;
    const int z = blockIdx.x >> 10;
    u16* row = S + ((size_t)z << 20) + ((size_t)t << 10);
    const int n = t + 1;
    const int tid = threadIdx.x;
    const int lane = tid & 63, wave = tid >> 6;
    const int c0 = tid * 4;

    ushort4 rv = ((const ushort4*)row)[tid];
    float v0 = (c0 + 0 < n) ? 0.125f * b2f(rv.x) : -1e30f;
    float v1 = (c0 + 1 < n) ? 0.125f * b2f(rv.y) : -1e30f;
    float v2 = (c0 + 2 < n) ? 0.125f * b2f(rv.z) : -1e30f;
    float v3 = (c0 + 3 < n) ? 0.125f * b2f(rv.w) : -1e30f;

    float mx = fmaxf(fmaxf(v0, v1), fmaxf(v2, v3));
#pragma unroll
    for (int off = 32; off; off >>= 1) mx = fmaxf(mx, __shfl_down(mx, off));
    if (lane == 0) red[wave] = mx;
    __syncthreads();
    if (tid == 0) red[4] = fmaxf(fmaxf(red[0], red[1]), fmaxf(red[2], red[3]));
    __syncthreads();
    const float M = red[4];

    float e0 = (c0 + 0 < n) ? __expf(v0 - M) : 0.f;
    float e1 = (c0 + 1 < n) ? __expf(v1 - M) : 0.f;
    float e2 = (c0 + 2 < n) ? __expf(v2 - M) : 0.f;
    float e3 = (c0 + 3 < n) ? __expf(v3 - M) : 0.f;

    float sum = e0 + e1 + e2 + e3;
#pragma unroll
    for (int off = 32; off; off >>= 1) sum += __shfl_down(sum, off);
    if (lane == 0) red[wave] = sum;
    __syncthreads();
    if (tid == 0) red[5] = red[0] + red[1] + red[2] + red[3];
    __syncthreads();
    const float inv = 1.0f / red[5];

    ushort4 o;
    o.x = f2b(e0 * inv); o.y = f2b(e1 * inv);
    o.z = f2b(e2 * inv); o.w = f2b(e3 * inv);
    ((ushort4*)row)[tid] = o;
}

// u1 = silu(u1) * u2   — ushort8 vectorized
__global__ void silu_mul_k(u16* __restrict__ u1, const u16* __restrict__ u2)
{
    size_t idx = (size_t)blockIdx.x * 256 + threadIdx.x;   // 720896 vec8
    u16x8 a8 = ((const u16x8*)u1)[idx];
    u16x8 b8 = ((const u16x8*)u2)[idx];
    u16x8 o;
#pragma unroll
    for (int j = 0; j < 8; ++j) {
        float a = b2f(a8[j]);
        float m = a / (1.f + __expf(-a));
        o[j] = f2b(m * b2f(b8[j]));
    }
    ((u16x8*)u1)[idx] = o;
}

// ---------------------------------------------------------------------------
static inline void launch_gemm(bool add, const u16* A, const u16* Bm, void* C,
                               int M, int N, int K, int lda, int ldb, int ldc,
                               int zdim, int nhDiv,
                               long sAb, long sAh, long sBb, long sBh,
                               long sCb, long sCh, int kSplit, int flags,
                               hipStream_t stream)
{
    dim3 g((N + 127) / 128, M / 128, zdim);
    if (add)
        gemm_bt<1><<<g, 256, 0, stream>>>(A, Bm, nullptr, (float*)C,
            M, N, K, lda, ldb, ldc, nhDiv, sAb, sAh, sBb, sBh, sCb, sCh,
            kSplit, flags);
    else
        gemm_bt<0><<<g, 256, 0, stream>>>(A, Bm, (u16*)C, nullptr,
            M, N, K, lda, ldb, ldc, nhDiv, sAb, sAh, sBb, sBh, sCb, sCh,
            kSplit, flags);
}

static inline void launch_cvt(const void* src, u16* dst, long perV,
                              long dstStrideV, long dstOffV, int chunks,
                              const int* flag, hipStream_t stream)
{
    long bx = (perV + 255) / 256; if (bx > 512) bx = 512;
    dim3 g((unsigned)bx, (unsigned)chunks, 1);
    cvt_k<<<g, 256, 0, stream>>>(src, dst, perV, dstStrideV, dstOffV, flag);
}

extern "C" void kernel_launch(void* const* d_in, const int* in_sizes, int n_in,
                              void* d_out, int out_size, void* d_ws, size_t ws_size,
                              hipStream_t stream)
{
    char* w = (char*)d_ws;
    float* h   = (float*)w;                          // [0,8) MB fp32 residual
    u16* a     = (u16*)(w + (8u  << 20));            // [8,12)
    u16* qkv   = (u16*)(w + (12u << 20));            // [12,24)  [2048][3072]
    u16* vt    = (u16*)(w + (24u << 20));            // [24,28)
    u16* y     = (u16*)(w + (28u << 20));            // [28,32)
    u16* S     = (u16*)(w + (32u << 20));            // [32,64)  16 heads x 1M
    u16* u1    = S;                                  // MLP overlaps S lifetime
    u16* u2    = S + (size_t)2048 * HFF_;

    // bf16 weight copies (relayout) above 64 MB — same footprint as before.
    size_t off = (size_t)64 << 20;
    u16* cx    = (u16*)(w + off); off += ((size_t)B_*T_*9*2   + 255) & ~(size_t)255;
    u16* cwin  = (u16*)(w + off); off += ((size_t)C_*9*2      + 255) & ~(size_t)255;
    u16* cwqkv = (u16*)(w + off); off += (size_t)L_*3072*1024*2;   // fused q|k|v
    u16* cwo   = (u16*)(w + off); off += (size_t)L_*C_*C_*2;
    u16* cw12  = (u16*)(w + off); off += (size_t)L_*2*HFF_*C_*2;   // fused w1|w2
    u16* cw3   = (u16*)(w + off); off += (size_t)L_*C_*HFF_*2;
    u16* cg1   = (u16*)(w + off); off += ((size_t)L_*C_*2 + 255) & ~(size_t)255;
    u16* cg2   = (u16*)(w + off); off += ((size_t)L_*C_*2 + 255) & ~(size_t)255;
    u16* cgf   = (u16*)(w + off); off += ((size_t)C_*2    + 255) & ~(size_t)255;
    int* flag  = (int*)(w + off); off += 256;
    float2* rtab = (float2*)(w + off);               // 1024*32*8 = 256 KB

    detect_k<<<1, 64, 0, stream>>>((const unsigned int*)d_in[0], flag);

    const long CCv  = (long)C_ * C_ / 4;        // 262144
    const long HCv  = (long)HFF_ * C_ / 4;      // 720896
    launch_cvt(d_in[0],  cx,    (long)B_*T_*9/4, 0, 0, 1, flag, stream);
    launch_cvt(d_in[1],  cwin,  (long)C_*9/4,    0, 0, 1, flag, stream);
    launch_cvt(d_in[2],  cwqkv, CCv,   3*CCv, 0,     L_, flag, stream);  // wq
    launch_cvt(d_in[3],  cwqkv, 2*CCv, 3*CCv, CCv,   L_, flag, stream);  // wkv
    launch_cvt(d_in[4],  cwo,   CCv,   CCv,   0,     L_, flag, stream);
    launch_cvt(d_in[5],  cw12,  HCv,   2*HCv, 0,     L_, flag, stream);  // w1
    launch_cvt(d_in[6],  cw12,  HCv,   2*HCv, HCv,   L_, flag, stream);  // w2
    launch_cvt(d_in[7],  cw3,   HCv,   HCv,   0,     L_, flag, stream);
    launch_cvt(d_in[8],  cg1,   (long)L_*C_/4, 0, 0, 1, flag, stream);
    launch_cvt(d_in[9],  cg2,   (long)L_*C_/4, 0, 0, 1, flag, stream);
    launch_cvt(d_in[10], cgf,   (long)C_/4,    0, 0, 1, flag, stream);

    rope_tab_k<<<128, 256, 0, stream>>>(rtab);

    const long TC  = (long)T_ * C_;      // 1M
    const long TT  = (long)T_ * T_;      // 1M
    const long TQ  = (long)T_ * 3072;    // qkv row-block per batch

    input_proj_k<<<8192, 256, 0, stream>>>(cx, cwin, h);

    for (int l = 0; l < L_; ++l) {
        const u16* wqkv_l = cwqkv + (size_t)l * 3072 * 1024;
        const u16* wo_l   = cwo   + (size_t)l * C_ * C_;
        const u16* w12_l  = cw12  + (size_t)l * 2 * HFF_ * C_;
        const u16* w3_l   = cw3   + (size_t)l * C_ * HFF_;

        // --- attention ---
        rms_k<<<2048, 256, 0, stream>>>(h, cg1 + l * C_, a, 0, flag);
        // qkv[2048][3072] = a @ [wq|wk|wv]^T   (z=3 chunks of N=1024)
        launch_gemm(false, a, wqkv_l, qkv, 2048, 1024, 1024, 1024, 1024, 3072,
                    3, 3, 0, 0, 0, (long)C_*C_, 0, 1024, 1, 0, stream);
        rope_k<<<4096, 256, 0, stream>>>(qkv, rtab);
        vtrans_k<<<512, 256, 0, stream>>>(qkv, vt);

        for (int b = 0; b < B_; ++b) {    // per-batch attention (S = 32 MB)
            const u16* qb = qkv + (size_t)b * TQ;          // q cols 0..1023
            const u16* kb = qb + 1024;                     // k cols
            const u16* vtb = vt + (size_t)b * NH_ * DH_ * T_;
            u16* yb        = y  + (size_t)b * TC;
            // S[h,t,s] = q . k   (z = head, K=64); skip above-diagonal blocks
            launch_gemm(false, qb, kb, S, 1024, 1024, 64, 3072, 3072, 1024,
                        16, 16, 0, 64, 0, 64, 0, TT, 1, 1, stream);
            softmax_k<<<16 * 1024, 256, 0, stream>>>(S);
            // y[t, h*64+d] = P . V^T   (N=64); truncate K at causal boundary
            launch_gemm(false, S, vtb, yb, 1024, 64, 1024, 1024, 1024, 1024,
                        16, 16, 0, TT, 0, (long)DH_*T_, 0, DH_, 1, 2, stream);
        }
        // h += y @ wo^T   (split-K x4)
        launch_gemm(true, y, wo_l, h, 2048, 1024, 1024, 1024, 1024, 1024,
                    4, 1, 0, 0, 0, 0, 0, 0, 4, 0, stream);

        // --- MLP ---
        rms_k<<<2048, 256, 0, stream>>>(h, cg2 + l * C_, a, 0, flag);
        // [u1|u2] = a @ [w1|w2]^T   (z=2 chunks of N=2816)
        launch_gemm(false, a, w12_l, u1, 2048, HFF_, 1024, 1024, 1024, HFF_,
                    2, 2, 0, 0, 0, (long)HFF_*C_, 0, (long)2048*HFF_, 1, 0, stream);
        silu_mul_k<<<2816, 256, 0, stream>>>(u1, u2);
        // h += u1 @ w3^T   (split-K x4, K=2816 -> 704 per slice)
        launch_gemm(true, u1, w3_l, h, 2048, 1024, HFF_, HFF_, HFF_, 1024,
                    4, 1, 0, 0, 0, 0, 0, 0, 4, 0, stream);
    }

    rms_k<<<2048, 256, 0, stream>>>(h, cgf, d_out, 1, flag);
}

// Round 2
// 1045.561 us; speedup vs baseline: 1.2613x; 1.2613x over previous
//
#include <hip/hip_runtime.h>
#include <hip/hip_bf16.h>

// LagLlama forward. fp32/bf16 input autodetect -> bf16 copies in ws.
// fp32 residual stream. Round 7 = R6 + fused flash attention (replaces
// scores GEMM + softmax + PV GEMM + S traffic) + bijective XCD swizzle in
// gemm_bt (T1) for L2 locality on the dense GEMMs.
// B=2 T=1024 C=1024 NH=16 DH=64 L=4 HFF=2816

#define B_   2
#define T_   1024
#define C_   1024
#define NH_  16
#define DH_  64
#define L_   4
#define HFF_ 2816
#define EPS_ 1e-5f

typedef unsigned short u16;
typedef short bf16x8 __attribute__((ext_vector_type(8)));
typedef unsigned short u16x8 __attribute__((ext_vector_type(8)));
typedef float f32x4 __attribute__((ext_vector_type(4)));

__device__ __forceinline__ float b2f(u16 u) {
    union { unsigned int i; float f; } v; v.i = ((unsigned int)u) << 16; return v.f;
}
__device__ __forceinline__ u16 f2b(float f) {
    union { unsigned int i; float f; } v; v.f = f;
    unsigned int r = (v.i + 0x7fff + ((v.i >> 16) & 1)) >> 16;
    return (u16)r;
}

// flag: 0 = inputs are bf16, 1 = inputs are fp32 (detected from x's raw bits)
__global__ void detect_k(const unsigned int* __restrict__ xw, int* __restrict__ flag)
{
    int tid = threadIdx.x;
    int cnt = 0;
#pragma unroll
    for (int i = 0; i < 4; ++i) {
        unsigned int w = xw[tid * 4 + i];
        unsigned int e = (w >> 7) & 0xFF;
        if (e >= 0x70 && e <= 0x87) cnt++;
    }
#pragma unroll
    for (int off = 32; off; off >>= 1) cnt += __shfl_down(cnt, off);
    if (tid == 0) flag[0] = (cnt > 128) ? 0 : 1;
}

// Relayout+convert: for chunk y (blockIdx.y), vec4-index i:
//   dst4[y*dstStrideV + dstOffV + i] = cvt(src4[y*perV + i])
__global__ void cvt_k(const void* __restrict__ src, u16* __restrict__ dst,
                      long perV, long dstStrideV, long dstOffV,
                      const int* __restrict__ flag)
{
    const int f = flag[0];
    long y = blockIdx.y;
    long i = (long)blockIdx.x * 256 + threadIdx.x;
    long stride = (long)gridDim.x * 256;
    for (; i < perV; i += stride) {
        long so = y * perV + i;
        long dj = y * dstStrideV + dstOffV + i;
        ushort4 o;
        if (f) {
            float4 v = ((const float4*)src)[so];
            o.x = f2b(v.x); o.y = f2b(v.y); o.z = f2b(v.z); o.w = f2b(v.w);
        } else {
            o = ((const ushort4*)src)[so];
        }
        ((ushort4*)dst)[dj] = o;
    }
}

// ---------------------------------------------------------------------------
// Batched GEMM: C[m,n] = sum_k A[m,k] * B[n,k]   (A: MxK lda, B: NxK ldb)
// MODE 0: write bf16 to Cb; z = batch (bb=z/nhDiv, hh=z%nhDiv), offsets
//         bb*s?b + hh*s?h (elements). N per sub-gemm; tail via clamp+mask.
// MODE 1: z = K-slice (kSplit slices); atomicAdd fp32 into Cf.
// M % 128 == 0; K (or K/kSplit) % 32 == 0.
// Bijective XCD swizzle (m204): each of the 8 XCDs gets a contiguous run of
// linearized workgroup IDs -> col-blocks sharing an A row-panel co-reside in
// one XCD's L2 (fixes near-zero L2 reuse seen as 2.8x HBM over-fetch).
// ---------------------------------------------------------------------------
template<int MODE>
__global__ __launch_bounds__(256, 2)
void gemm_bt(const u16* __restrict__ A, const u16* __restrict__ Bm,
             u16* __restrict__ Cb, float* __restrict__ Cf,
             int M, int N, int K, int lda, int ldb, int ldc,
             int nhDiv, long sAb, long sAh, long sBb, long sBh,
             long sCb, long sCh, int kSplit)
{
    __shared__ __align__(16) u16 tA[128 * 32];
    __shared__ __align__(16) u16 tB[128 * 32];

    // --- XCD-aware bijective remap of the linear workgroup id ---
    const unsigned nx = gridDim.x, ny = gridDim.y;
    const unsigned nwg = nx * ny * gridDim.z;
    const unsigned lin = blockIdx.x + nx * (blockIdx.y + ny * blockIdx.z);
    const unsigned qd = nwg >> 3, rm = nwg & 7;
    const unsigned xcd = lin & 7, pos = lin >> 3;
    const unsigned wg = (xcd < rm ? xcd * (qd + 1)
                                  : rm * (qd + 1) + (xcd - rm) * qd) + pos;
    const unsigned bx = wg % nx;
    const unsigned tmp = wg / nx;
    const unsigned by = tmp % ny;
    const unsigned bz = tmp / ny;

    const int z = (int)bz;
    int kBeg = 0, kEnd = K;
    const u16* Ab = A;
    const u16* Bb = Bm;
    long cOff = 0;
    if (MODE == 1) {
        int ks = K / kSplit;
        kBeg = z * ks; kEnd = kBeg + ks;
    } else {
        int bb = z / nhDiv;
        int hh = z - bb * nhDiv;
        Ab += bb * sAb + hh * sAh;
        Bb += bb * sBb + hh * sBh;
        cOff = bb * sCb + hh * sCh;
    }

    const int row0 = by * 128;
    const int col0 = bx * 128;

    const int tid  = threadIdx.x;
    const int lane = tid & 63;
    const int wave = tid >> 6;
    const int wr = wave >> 1, wc = wave & 1;   // 2x2 waves of 64x64
    const int lrow = lane & 15;
    const int kg   = lane >> 4;

    f32x4 acc[4][4] = {};

    for (int k0 = kBeg; k0 < kEnd; k0 += 32) {
        __syncthreads();   // prior iter's LDS reads done before overwrite
#pragma unroll
        for (int i = 0; i < 2; ++i) {          // A tile: 512 x 16B chunks
            int chunk = i * 256 + tid;
            int r = chunk >> 2, cg = chunk & 3;
            const u16* ga = Ab + (long)(row0 + r) * lda + (k0 + cg * 8);
            u16* la = tA + (size_t)(i * 256 + wave * 64) * 8;  // wave-uniform
            __builtin_amdgcn_global_load_lds(
                (const __attribute__((address_space(1))) void*)ga,
                (__attribute__((address_space(3))) void*)la, 16, 0, 0);
        }
#pragma unroll
        for (int i = 0; i < 2; ++i) {          // B tile
            int chunk = i * 256 + tid;
            int r = chunk >> 2, cg = chunk & 3;
            int rB = col0 + r; if (rB > N - 1) rB = N - 1;   // N-tail clamp
            const u16* gb = Bb + (long)rB * ldb + (k0 + cg * 8);
            u16* lb = tB + (size_t)(i * 256 + wave * 64) * 8;
            __builtin_amdgcn_global_load_lds(
                (const __attribute__((address_space(1))) void*)gb,
                (__attribute__((address_space(3))) void*)lb, 16, 0, 0);
        }
        __syncthreads();

        bf16x8 af[4], bfr[4];
#pragma unroll
        for (int ti = 0; ti < 4; ++ti)
            af[ti] = *(const bf16x8*)&tA[(wr * 64 + ti * 16 + lrow) * 32 + kg * 8];
#pragma unroll
        for (int tj = 0; tj < 4; ++tj)
            bfr[tj] = *(const bf16x8*)&tB[(wc * 64 + tj * 16 + lrow) * 32 + kg * 8];
#pragma unroll
        for (int ti = 0; ti < 4; ++ti)
#pragma unroll
            for (int tj = 0; tj < 4; ++tj)
                acc[ti][tj] = __builtin_amdgcn_mfma_f32_16x16x32_bf16(
                    af[ti], bfr[tj], acc[ti][tj], 0, 0, 0);
    }

    // Epilogue: D[row = kg*4 + r][col = lane&15] per 16x16 tile.
    const int rbase = row0 + wr * 64;
    const int cbase = col0 + wc * 64 + lrow;
#pragma unroll
    for (int ti = 0; ti < 4; ++ti) {
#pragma unroll
        for (int r = 0; r < 4; ++r) {
            int row = rbase + ti * 16 + kg * 4 + r;
#pragma unroll
            for (int tj = 0; tj < 4; ++tj) {
                int col = cbase + tj * 16;
                if (col < N) {
                    long off = cOff + (long)row * ldc + col;
                    if (MODE == 0) Cb[off] = f2b(acc[ti][tj][r]);
                    else           atomicAdd(&Cf[off], acc[ti][tj][r]);
                }
            }
        }
    }
}

// ---------------------------------------------------------------------------
// Fused causal flash attention. One block = (b, head, 64 q-rows), 2 waves x
// 32 q-rows. K/V tiles (64 kv) staged to LDS via global_load_lds with the
// global source pre-swizzled (XOR granule ^ (row&7)) so swizzled ds_read_b128
// fragment loads are bank-conflict-free. S^T = K@Q^T puts the softmax
// reduction lane-local + 2 shfl_xor; P goes through a per-wave swizzled LDS
// tile into PV MFMA A-fragments. fp32 online softmax state; bf16 P.
// qkv: [b*1024+t][3072] (q|k|v, rope applied).  vt: [b,h,d,s].  y: [b*T][C].
// ---------------------------------------------------------------------------
__global__ __launch_bounds__(128, 2)
void flash_k(const u16* __restrict__ qkv, const u16* __restrict__ vt,
             u16* __restrict__ y)
{
    __shared__ __align__(16) u16 tK[64 * 64];
    __shared__ __align__(16) u16 tV[64 * 64];
    __shared__ __align__(16) u16 tP[2 * 32 * 64];

    const int bid = blockIdx.x;          // 512 = 2b * 16h * 16 q-tiles
    const int qt = bid & 15;
    const int hh = (bid >> 4) & 15;
    const int b  = bid >> 8;

    const int tid  = threadIdx.x;
    const int lane = tid & 63;
    const int w    = tid >> 6;           // wave 0/1
    const int l15  = lane & 15;
    const int kg   = lane >> 4;          // 0..3

    const int wq0 = qt * 64 + w * 32;    // wave's first q row
    u16* tPw = tP + w * 32 * 64;

    // Q fragments in registers: qf[qi][dk] = Q[wq0+qi*16+l15][dk*32+kg*8..+8]
    bf16x8 qf[2][2];
#pragma unroll
    for (int qi = 0; qi < 2; ++qi)
#pragma unroll
        for (int dk = 0; dk < 2; ++dk) {
            const u16* src = qkv + (size_t)(b * 1024 + wq0 + qi * 16 + l15) * 3072
                           + hh * 64 + dk * 32 + kg * 8;
            qf[qi][dk] = *(const bf16x8*)src;
        }

    f32x4 acc_o[2][4] = {};
    float mrun[2] = { -3e38f, -3e38f };
    float lrun[2] = { 0.f, 0.f };

    const u16* Kg0 = qkv + (size_t)(b * 1024) * 3072 + 1024 + hh * 64;
    const u16* Vg0 = vt + (size_t)((b * 16 + hh) * 64) * 1024;

    for (int j = 0; j <= qt; ++j) {
        __syncthreads();                 // prior tile's K/V reads done
        // stage K (rows=kv, 64x64) and V^T (rows=d, 64x64), source-swizzled
#pragma unroll
        for (int i = 0; i < 4; ++i) {
            int chunk = i * 128 + tid;   // granule id 0..511
            int row = chunk >> 3, gc = chunk & 7;
            int sgc = gc ^ (row & 7);
            const u16* ga = Kg0 + (size_t)(j * 64 + row) * 3072 + sgc * 8;
            u16* la = tK + (size_t)(i * 128 + w * 64) * 8;   // wave-uniform
            __builtin_amdgcn_global_load_lds(
                (const __attribute__((address_space(1))) void*)ga,
                (__attribute__((address_space(3))) void*)la, 16, 0, 0);
            const u16* gb = Vg0 + (size_t)row * 1024 + j * 64 + sgc * 8;
            u16* lb = tV + (size_t)(i * 128 + w * 64) * 8;
            __builtin_amdgcn_global_load_lds(
                (const __attribute__((address_space(1))) void*)gb,
                (__attribute__((address_space(3))) void*)lb, 16, 0, 0);
        }
        __syncthreads();

        // S^T[kv][q] = K @ Q^T : s[kvt][qi]; C/D col=q=l15, row=kv=kg*4+r
        f32x4 s[4][2] = {};
#pragma unroll
        for (int dk = 0; dk < 2; ++dk) {
            bf16x8 ak[4];
#pragma unroll
            for (int kvt = 0; kvt < 4; ++kvt) {
                int row = kvt * 16 + l15;
                int g = (dk * 4 + kg) ^ (row & 7);
                ak[kvt] = *(const bf16x8*)&tK[row * 64 + g * 8];
            }
#pragma unroll
            for (int kvt = 0; kvt < 4; ++kvt)
#pragma unroll
                for (int qi = 0; qi < 2; ++qi)
                    s[kvt][qi] = __builtin_amdgcn_mfma_f32_16x16x32_bf16(
                        ak[kvt], qf[qi][dk], s[kvt][qi], 0, 0, 0);
        }

        // scale + causal mask (only the diagonal tile j==qt) + row max
        float tmax[2] = { -3e38f, -3e38f };
        const bool maskt = (j == qt);
#pragma unroll
        for (int kvt = 0; kvt < 4; ++kvt)
#pragma unroll
            for (int qi = 0; qi < 2; ++qi) {
                f32x4 v = s[kvt][qi];
#pragma unroll
                for (int r = 0; r < 4; ++r) {
                    float sv = v[r] * 0.125f;
                    if (maskt) {
                        int kv_a = j * 64 + kvt * 16 + kg * 4 + r;
                        int q_a  = wq0 + qi * 16 + l15;
                        if (kv_a > q_a) sv = -3e38f;
                    }
                    v[r] = sv;
                    tmax[qi] = fmaxf(tmax[qi], sv);
                }
                s[kvt][qi] = v;
            }
#pragma unroll
        for (int qi = 0; qi < 2; ++qi) {
            tmax[qi] = fmaxf(tmax[qi], __shfl_xor(tmax[qi], 16));
            tmax[qi] = fmaxf(tmax[qi], __shfl_xor(tmax[qi], 32));
        }

        float sf[2], mn[2];
#pragma unroll
        for (int qi = 0; qi < 2; ++qi) {
            mn[qi] = fmaxf(mrun[qi], tmax[qi]);
            sf[qi] = __expf(mrun[qi] - mn[qi]);   // first tile: exp(-3e38)=0
            mrun[qi] = mn[qi];
        }

        // rescale O: its rows are q = qi*16 + kg*4 + ro -> fetch factor from
        // the lane holding that q-column's softmax chain (lane = kg*4+ro)
#pragma unroll
        for (int qi = 0; qi < 2; ++qi)
#pragma unroll
            for (int ro = 0; ro < 4; ++ro) {
                float f = __shfl(sf[qi], kg * 4 + ro);
#pragma unroll
                for (int dj = 0; dj < 4; ++dj)
                    acc_o[qi][dj][ro] *= f;
            }

        // exp, row-sum, pack bf16, write P[q][kv] to swizzled per-wave LDS
        float tsum[2] = { 0.f, 0.f };
#pragma unroll
        for (int kvt = 0; kvt < 4; ++kvt)
#pragma unroll
            for (int qi = 0; qi < 2; ++qi) {
                f32x4 v = s[kvt][qi];
                float p0 = __expf(v[0] - mn[qi]);
                float p1 = __expf(v[1] - mn[qi]);
                float p2 = __expf(v[2] - mn[qi]);
                float p3 = __expf(v[3] - mn[qi]);
                tsum[qi] += p0 + p1 + p2 + p3;
                ushort4 pk;
                pk.x = f2b(p0); pk.y = f2b(p1); pk.z = f2b(p2); pk.w = f2b(p3);
                int row = qi * 16 + l15;
                int g = (kvt * 2 + (kg >> 1)) ^ (row & 7);
                *(ushort4*)&tPw[row * 64 + g * 8 + (kg & 1) * 4] = pk;
            }
#pragma unroll
        for (int qi = 0; qi < 2; ++qi) {
            tsum[qi] += __shfl_xor(tsum[qi], 16);
            tsum[qi] += __shfl_xor(tsum[qi], 32);
            lrun[qi] = lrun[qi] * sf[qi] + tsum[qi];
        }

        // O += P @ V : A = P[q][kv] (own-wave LDS), B = V^T[d][kv]
#pragma unroll
        for (int ki = 0; ki < 2; ++ki) {
            bf16x8 ap[2], bv[4];
#pragma unroll
            for (int qi = 0; qi < 2; ++qi) {
                int row = qi * 16 + l15;
                int g = (ki * 4 + kg) ^ (row & 7);
                ap[qi] = *(const bf16x8*)&tPw[row * 64 + g * 8];
            }
#pragma unroll
            for (int dj = 0; dj < 4; ++dj) {
                int row = dj * 16 + l15;
                int g = (ki * 4 + kg) ^ (row & 7);
                bv[dj] = *(const bf16x8*)&tV[row * 64 + g * 8];
            }
#pragma unroll
            for (int qi = 0; qi < 2; ++qi)
#pragma unroll
                for (int dj = 0; dj < 4; ++dj)
                    acc_o[qi][dj] = __builtin_amdgcn_mfma_f32_16x16x32_bf16(
                        ap[qi], bv[dj], acc_o[qi][dj], 0, 0, 0);
        }
    }

    // y[b, q, hh*64 + d] = O / l
#pragma unroll
    for (int qi = 0; qi < 2; ++qi) {
        float inv = 1.0f / lrun[qi];
#pragma unroll
        for (int ro = 0; ro < 4; ++ro) {
            float iv = __shfl(inv, kg * 4 + ro);
            size_t rowo = (size_t)(b * 1024 + wq0 + qi * 16 + kg * 4 + ro) * 1024
                        + hh * 64 + l15;
#pragma unroll
            for (int dj = 0; dj < 4; ++dj)
                y[rowo + dj * 16] = f2b(acc_o[qi][dj][ro] * iv);
        }
    }
}

// h[bt,c] = sum_f x[bt,f] * w_in[c,f]   (K=9, fp32 out)
__global__ void input_proj_k(const u16* __restrict__ x, const u16* __restrict__ w,
                             float* __restrict__ h)
{
    int idx = blockIdx.x * 256 + threadIdx.x;      // 2M
    int bt = idx >> 10, c = idx & 1023;
    float s = 0.f;
#pragma unroll
    for (int f = 0; f < 9; ++f) s += b2f(x[bt * 9 + f]) * b2f(w[c * 9 + f]);
    h[idx] = s;
}

// out[row,:] = h * rsqrt(mean(h^2)+eps) * g.  isFinal&&flag -> fp32 out.
// Vectorized: 256 threads x float4 == C=1024 exactly.
__global__ void rms_k(const float* __restrict__ h, const u16* __restrict__ g,
                      void* __restrict__ out, int isFinal,
                      const int* __restrict__ flag)
{
    __shared__ float red[8];
    const int row = blockIdx.x;
    const int tid = threadIdx.x;
    float4 v = ((const float4*)(h + (size_t)row * C_))[tid];
    float ss = v.x * v.x + v.y * v.y + v.z * v.z + v.w * v.w;
#pragma unroll
    for (int off = 32; off; off >>= 1) ss += __shfl_down(ss, off);
    int lane = tid & 63, wave = tid >> 6;
    if (lane == 0) red[wave] = ss;
    __syncthreads();
    if (tid == 0)
        red[4] = rsqrtf((red[0] + red[1] + red[2] + red[3]) / (float)C_ + EPS_);
    __syncthreads();
    const float r = red[4];
    ushort4 gv = ((const ushort4*)g)[tid];
    float o0 = v.x * r * b2f(gv.x);
    float o1 = v.y * r * b2f(gv.y);
    float o2 = v.z * r * b2f(gv.z);
    float o3 = v.w * r * b2f(gv.w);
    if (isFinal && flag[0]) {
        ((float4*)out)[(size_t)row * 256 + tid] = make_float4(o0, o1, o2, o3);
    } else {
        ushort4 o; o.x = f2b(o0); o.y = f2b(o1); o.z = f2b(o2); o.w = f2b(o3);
        ((ushort4*)out)[(size_t)row * 256 + tid] = o;
    }
}

// cos/sin table: tab[t*32+i] = {cos,sin}(t * 10000^(-i/32)), t<1024, i<32
__global__ void rope_tab_k(float2* __restrict__ tab)
{
    int idx = blockIdx.x * 256 + threadIdx.x;      // 32768
    int i = idx & 31;
    int t = idx >> 5;
    float invf = powf(10000.0f, -(float)i / 32.0f);
    float fr = (float)t * invf;
    tab[idx] = make_float2(cosf(fr), sinf(fr));
}

// RoPE in place on qkv[b,t,:]: q cols 0..1023, k cols 1024..2047 (ld 3072)
__global__ void rope_k(u16* __restrict__ qkv, const float2* __restrict__ tab)
{
    int idx = blockIdx.x * 256 + threadIdx.x;      // B*T*NH*32 = 1M
    int i = idx & 31;
    int hh = (idx >> 5) & 15;
    int t = (idx >> 9) & 1023;
    int b = idx >> 19;
    float2 cs = tab[(t << 5) + i];
    float cf = cs.x, sf = cs.y;

    size_t base = (size_t)(b * 1024 + t) * 3072 + hh * 64 + i;
    float x1 = b2f(qkv[base]), x2 = b2f(qkv[base + 32]);
    qkv[base]      = f2b(x1 * cf - x2 * sf);
    qkv[base + 32] = f2b(x2 * cf + x1 * sf);

    size_t kb = base + 1024;
    x1 = b2f(qkv[kb]); x2 = b2f(qkv[kb + 32]);
    qkv[kb]      = f2b(x1 * cf - x2 * sf);
    qkv[kb + 32] = f2b(x2 * cf + x1 * sf);
}

// vt[b,h,d,s] = qkv[b,s, 2048 + h*64 + d]  — LDS-tiled 64x64 transpose,
// coalesced vector access on both global sides.
__global__ void vtrans_k(const u16* __restrict__ qkv, u16* __restrict__ vt)
{
    __shared__ u16 tile[64][68];                   // pad 4 u16
    const int bz = blockIdx.x;                     // 512 = 2b * 16h * 16s-tiles
    const int s0 = (bz & 15) << 6;
    const int hh = (bz >> 4) & 15;
    const int b  = bz >> 8;
    const int tid = threadIdx.x;
#pragma unroll
    for (int it = 0; it < 2; ++it) {
        int id = it * 256 + tid;                   // 0..511
        int r  = id >> 3;                          // s-row within tile
        int cg = id & 7;                           // 8-wide d chunk
        const u16* src = qkv + (size_t)(b * 1024 + s0 + r) * 3072
                             + 2048 + hh * 64 + cg * 8;
        ushort4 a0 = *(const ushort4*)src;
        ushort4 a1 = *(const ushort4*)(src + 4);
        *(ushort4*)&tile[r][cg * 8]     = a0;
        *(ushort4*)&tile[r][cg * 8 + 4] = a1;
    }
    __syncthreads();
#pragma unroll
    for (int it = 0; it < 2; ++it) {
        int id = it * 256 + tid;
        int d  = id >> 3;                          // d row of output
        int cg = id & 7;                           // 8-wide s chunk
        ushort4 o0, o1;
        o0.x = tile[cg * 8 + 0][d]; o0.y = tile[cg * 8 + 1][d];
        o0.z = tile[cg * 8 + 2][d]; o0.w = tile[cg * 8 + 3][d];
        o1.x = tile[cg * 8 + 4][d]; o1.y = tile[cg * 8 + 5][d];
        o1.z = tile[cg * 8 + 6][d]; o1.w = tile[cg * 8 + 7][d];
        u16* dst = vt + (size_t)((b * 16 + hh) * 64 + d) * 1024 + s0 + cg * 8;
        *(ushort4*)dst       = o0;
        *(ushort4*)(dst + 4) = o1;
    }
}

// u1 = silu(u1) * u2   — ushort8 vectorized
__global__ void silu_mul_k(u16* __restrict__ u1, const u16* __restrict__ u2)
{
    size_t idx = (size_t)blockIdx.x * 256 + threadIdx.x;   // 720896 vec8
    u16x8 a8 = ((const u16x8*)u1)[idx];
    u16x8 b8 = ((const u16x8*)u2)[idx];
    u16x8 o;
#pragma unroll
    for (int j = 0; j < 8; ++j) {
        float a = b2f(a8[j]);
        float m = a / (1.f + __expf(-a));
        o[j] = f2b(m * b2f(b8[j]));
    }
    ((u16x8*)u1)[idx] = o;
}

// ---------------------------------------------------------------------------
static inline void launch_gemm(bool add, const u16* A, const u16* Bm, void* C,
                               int M, int N, int K, int lda, int ldb, int ldc,
                               int zdim, int nhDiv,
                               long sAb, long sAh, long sBb, long sBh,
                               long sCb, long sCh, int kSplit, hipStream_t stream)
{
    dim3 g((N + 127) / 128, M / 128, zdim);
    if (add)
        gemm_bt<1><<<g, 256, 0, stream>>>(A, Bm, nullptr, (float*)C,
            M, N, K, lda, ldb, ldc, nhDiv, sAb, sAh, sBb, sBh, sCb, sCh, kSplit);
    else
        gemm_bt<0><<<g, 256, 0, stream>>>(A, Bm, (u16*)C, nullptr,
            M, N, K, lda, ldb, ldc, nhDiv, sAb, sAh, sBb, sBh, sCb, sCh, kSplit);
}

static inline void launch_cvt(const void* src, u16* dst, long perV,
                              long dstStrideV, long dstOffV, int chunks,
                              const int* flag, hipStream_t stream)
{
    long bx = (perV + 255) / 256; if (bx > 512) bx = 512;
    dim3 g((unsigned)bx, (unsigned)chunks, 1);
    cvt_k<<<g, 256, 0, stream>>>(src, dst, perV, dstStrideV, dstOffV, flag);
}

extern "C" void kernel_launch(void* const* d_in, const int* in_sizes, int n_in,
                              void* d_out, int out_size, void* d_ws, size_t ws_size,
                              hipStream_t stream)
{
    char* w = (char*)d_ws;
    float* h   = (float*)w;                          // [0,8) MB fp32 residual
    u16* a     = (u16*)(w + (8u  << 20));            // [8,12)
    u16* qkv   = (u16*)(w + (12u << 20));            // [12,24)  [2048][3072]
    u16* vt    = (u16*)(w + (24u << 20));            // [24,28)
    u16* y     = (u16*)(w + (28u << 20));            // [28,32)
    u16* u1    = (u16*)(w + (32u << 20));            // [32,64) MLP buffers
    u16* u2    = u1 + (size_t)2048 * HFF_;

    // bf16 weight copies (relayout) above 64 MB — same footprint as before.
    size_t off = (size_t)64 << 20;
    u16* cx    = (u16*)(w + off); off += ((size_t)B_*T_*9*2   + 255) & ~(size_t)255;
    u16* cwin  = (u16*)(w + off); off += ((size_t)C_*9*2      + 255) & ~(size_t)255;
    u16* cwqkv = (u16*)(w + off); off += (size_t)L_*3072*1024*2;   // fused q|k|v
    u16* cwo   = (u16*)(w + off); off += (size_t)L_*C_*C_*2;
    u16* cw12  = (u16*)(w + off); off += (size_t)L_*2*HFF_*C_*2;   // fused w1|w2
    u16* cw3   = (u16*)(w + off); off += (size_t)L_*C_*HFF_*2;
    u16* cg1   = (u16*)(w + off); off += ((size_t)L_*C_*2 + 255) & ~(size_t)255;
    u16* cg2   = (u16*)(w + off); off += ((size_t)L_*C_*2 + 255) & ~(size_t)255;
    u16* cgf   = (u16*)(w + off); off += ((size_t)C_*2    + 255) & ~(size_t)255;
    int* flag  = (int*)(w + off); off += 256;
    float2* rtab = (float2*)(w + off);               // 1024*32*8 = 256 KB

    detect_k<<<1, 64, 0, stream>>>((const unsigned int*)d_in[0], flag);

    const long CCv  = (long)C_ * C_ / 4;        // 262144
    const long HCv  = (long)HFF_ * C_ / 4;      // 720896
    launch_cvt(d_in[0],  cx,    (long)B_*T_*9/4, 0, 0, 1, flag, stream);
    launch_cvt(d_in[1],  cwin,  (long)C_*9/4,    0, 0, 1, flag, stream);
    launch_cvt(d_in[2],  cwqkv, CCv,   3*CCv, 0,     L_, flag, stream);  // wq
    launch_cvt(d_in[3],  cwqkv, 2*CCv, 3*CCv, CCv,   L_, flag, stream);  // wkv
    launch_cvt(d_in[4],  cwo,   CCv,   CCv,   0,     L_, flag, stream);
    launch_cvt(d_in[5],  cw12,  HCv,   2*HCv, 0,     L_, flag, stream);  // w1
    launch_cvt(d_in[6],  cw12,  HCv,   2*HCv, HCv,   L_, flag, stream);  // w2
    launch_cvt(d_in[7],  cw3,   HCv,   HCv,   0,     L_, flag, stream);
    launch_cvt(d_in[8],  cg1,   (long)L_*C_/4, 0, 0, 1, flag, stream);
    launch_cvt(d_in[9],  cg2,   (long)L_*C_/4, 0, 0, 1, flag, stream);
    launch_cvt(d_in[10], cgf,   (long)C_/4,    0, 0, 1, flag, stream);

    rope_tab_k<<<128, 256, 0, stream>>>(rtab);

    input_proj_k<<<8192, 256, 0, stream>>>(cx, cwin, h);

    for (int l = 0; l < L_; ++l) {
        const u16* wqkv_l = cwqkv + (size_t)l * 3072 * 1024;
        const u16* wo_l   = cwo   + (size_t)l * C_ * C_;
        const u16* w12_l  = cw12  + (size_t)l * 2 * HFF_ * C_;
        const u16* w3_l   = cw3   + (size_t)l * C_ * HFF_;

        // --- attention ---
        rms_k<<<2048, 256, 0, stream>>>(h, cg1 + l * C_, a, 0, flag);
        // qkv[2048][3072] = a @ [wq|wk|wv]^T   (z=3 chunks of N=1024)
        launch_gemm(false, a, wqkv_l, qkv, 2048, 1024, 1024, 1024, 1024, 3072,
                    3, 3, 0, 0, 0, (long)C_*C_, 0, 1024, 1, stream);
        rope_k<<<4096, 256, 0, stream>>>(qkv, rtab);
        vtrans_k<<<512, 256, 0, stream>>>(qkv, vt);
        // fused flash attention -> y
        flash_k<<<512, 128, 0, stream>>>(qkv, vt, y);
        // h += y @ wo^T   (split-K x4)
        launch_gemm(true, y, wo_l, h, 2048, 1024, 1024, 1024, 1024, 1024,
                    4, 1, 0, 0, 0, 0, 0, 0, 4, stream);

        // --- MLP ---
        rms_k<<<2048, 256, 0, stream>>>(h, cg2 + l * C_, a, 0, flag);
        // [u1|u2] = a @ [w1|w2]^T   (z=2 chunks of N=2816)
        launch_gemm(false, a, w12_l, u1, 2048, HFF_, 1024, 1024, 1024, HFF_,
                    2, 2, 0, 0, 0, (long)HFF_*C_, 0, (long)2048*HFF_, 1, stream);
        silu_mul_k<<<2816, 256, 0, stream>>>(u1, u2);
        // h += u1 @ w3^T   (split-K x4, K=2816 -> 704 per slice)
        launch_gemm(true, u1, w3_l, h, 2048, 1024, HFF_, HFF_, HFF_, 1024,
                    4, 1, 0, 0, 0, 0, 0, 0, 4, stream);
    }

    rms_k<<<2048, 256, 0, stream>>>(h, cgf, d_out, 1, flag);
}

// Round 3
// 984.632 us; speedup vs baseline: 1.3394x; 1.0619x over previous
//
#include <hip/hip_runtime.h>
#include <hip/hip_bf16.h>

// LagLlama forward. fp32/bf16 input autodetect -> bf16 copies in ws.
// fp32 residual stream. Round 8 = R7 + flash_k v2: 4 waves/block (16 q-rows
// each), double-buffered K/V LDS staging (prefetch overlaps compute), XCD
// swizzle on the flash grid. Dense GEMM path unchanged.
// B=2 T=1024 C=1024 NH=16 DH=64 L=4 HFF=2816

#define B_   2
#define T_   1024
#define C_   1024
#define NH_  16
#define DH_  64
#define L_   4
#define HFF_ 2816
#define EPS_ 1e-5f

typedef unsigned short u16;
typedef short bf16x8 __attribute__((ext_vector_type(8)));
typedef unsigned short u16x8 __attribute__((ext_vector_type(8)));
typedef float f32x4 __attribute__((ext_vector_type(4)));

__device__ __forceinline__ float b2f(u16 u) {
    union { unsigned int i; float f; } v; v.i = ((unsigned int)u) << 16; return v.f;
}
__device__ __forceinline__ u16 f2b(float f) {
    union { unsigned int i; float f; } v; v.f = f;
    unsigned int r = (v.i + 0x7fff + ((v.i >> 16) & 1)) >> 16;
    return (u16)r;
}

// flag: 0 = inputs are bf16, 1 = inputs are fp32 (detected from x's raw bits)
__global__ void detect_k(const unsigned int* __restrict__ xw, int* __restrict__ flag)
{
    int tid = threadIdx.x;
    int cnt = 0;
#pragma unroll
    for (int i = 0; i < 4; ++i) {
        unsigned int w = xw[tid * 4 + i];
        unsigned int e = (w >> 7) & 0xFF;
        if (e >= 0x70 && e <= 0x87) cnt++;
    }
#pragma unroll
    for (int off = 32; off; off >>= 1) cnt += __shfl_down(cnt, off);
    if (tid == 0) flag[0] = (cnt > 128) ? 0 : 1;
}

// Relayout+convert: for chunk y (blockIdx.y), vec4-index i:
//   dst4[y*dstStrideV + dstOffV + i] = cvt(src4[y*perV + i])
__global__ void cvt_k(const void* __restrict__ src, u16* __restrict__ dst,
                      long perV, long dstStrideV, long dstOffV,
                      const int* __restrict__ flag)
{
    const int f = flag[0];
    long y = blockIdx.y;
    long i = (long)blockIdx.x * 256 + threadIdx.x;
    long stride = (long)gridDim.x * 256;
    for (; i < perV; i += stride) {
        long so = y * perV + i;
        long dj = y * dstStrideV + dstOffV + i;
        ushort4 o;
        if (f) {
            float4 v = ((const float4*)src)[so];
            o.x = f2b(v.x); o.y = f2b(v.y); o.z = f2b(v.z); o.w = f2b(v.w);
        } else {
            o = ((const ushort4*)src)[so];
        }
        ((ushort4*)dst)[dj] = o;
    }
}

// ---------------------------------------------------------------------------
// Batched GEMM: C[m,n] = sum_k A[m,k] * B[n,k]   (A: MxK lda, B: NxK ldb)
// MODE 0: write bf16 to Cb; z = batch (bb=z/nhDiv, hh=z%nhDiv), offsets
//         bb*s?b + hh*s?h (elements). N per sub-gemm; tail via clamp+mask.
// MODE 1: z = K-slice (kSplit slices); atomicAdd fp32 into Cf.
// M % 128 == 0; K (or K/kSplit) % 32 == 0.
// Bijective XCD swizzle (m204) for L2 locality.
// ---------------------------------------------------------------------------
template<int MODE>
__global__ __launch_bounds__(256, 2)
void gemm_bt(const u16* __restrict__ A, const u16* __restrict__ Bm,
             u16* __restrict__ Cb, float* __restrict__ Cf,
             int M, int N, int K, int lda, int ldb, int ldc,
             int nhDiv, long sAb, long sAh, long sBb, long sBh,
             long sCb, long sCh, int kSplit)
{
    __shared__ __align__(16) u16 tA[128 * 32];
    __shared__ __align__(16) u16 tB[128 * 32];

    // --- XCD-aware bijective remap of the linear workgroup id ---
    const unsigned nx = gridDim.x, ny = gridDim.y;
    const unsigned nwg = nx * ny * gridDim.z;
    const unsigned lin = blockIdx.x + nx * (blockIdx.y + ny * blockIdx.z);
    const unsigned qd = nwg >> 3, rm = nwg & 7;
    const unsigned xcd = lin & 7, pos = lin >> 3;
    const unsigned wg = (xcd < rm ? xcd * (qd + 1)
                                  : rm * (qd + 1) + (xcd - rm) * qd) + pos;
    const unsigned bx = wg % nx;
    const unsigned tmp = wg / nx;
    const unsigned by = tmp % ny;
    const unsigned bz = tmp / ny;

    const int z = (int)bz;
    int kBeg = 0, kEnd = K;
    const u16* Ab = A;
    const u16* Bb = Bm;
    long cOff = 0;
    if (MODE == 1) {
        int ks = K / kSplit;
        kBeg = z * ks; kEnd = kBeg + ks;
    } else {
        int bb = z / nhDiv;
        int hh = z - bb * nhDiv;
        Ab += bb * sAb + hh * sAh;
        Bb += bb * sBb + hh * sBh;
        cOff = bb * sCb + hh * sCh;
    }

    const int row0 = by * 128;
    const int col0 = bx * 128;

    const int tid  = threadIdx.x;
    const int lane = tid & 63;
    const int wave = tid >> 6;
    const int wr = wave >> 1, wc = wave & 1;   // 2x2 waves of 64x64
    const int lrow = lane & 15;
    const int kg   = lane >> 4;

    f32x4 acc[4][4] = {};

    for (int k0 = kBeg; k0 < kEnd; k0 += 32) {
        __syncthreads();   // prior iter's LDS reads done before overwrite
#pragma unroll
        for (int i = 0; i < 2; ++i) {          // A tile: 512 x 16B chunks
            int chunk = i * 256 + tid;
            int r = chunk >> 2, cg = chunk & 3;
            const u16* ga = Ab + (long)(row0 + r) * lda + (k0 + cg * 8);
            u16* la = tA + (size_t)(i * 256 + wave * 64) * 8;  // wave-uniform
            __builtin_amdgcn_global_load_lds(
                (const __attribute__((address_space(1))) void*)ga,
                (__attribute__((address_space(3))) void*)la, 16, 0, 0);
        }
#pragma unroll
        for (int i = 0; i < 2; ++i) {          // B tile
            int chunk = i * 256 + tid;
            int r = chunk >> 2, cg = chunk & 3;
            int rB = col0 + r; if (rB > N - 1) rB = N - 1;   // N-tail clamp
            const u16* gb = Bb + (long)rB * ldb + (k0 + cg * 8);
            u16* lb = tB + (size_t)(i * 256 + wave * 64) * 8;
            __builtin_amdgcn_global_load_lds(
                (const __attribute__((address_space(1))) void*)gb,
                (__attribute__((address_space(3))) void*)lb, 16, 0, 0);
        }
        __syncthreads();

        bf16x8 af[4], bfr[4];
#pragma unroll
        for (int ti = 0; ti < 4; ++ti)
            af[ti] = *(const bf16x8*)&tA[(wr * 64 + ti * 16 + lrow) * 32 + kg * 8];
#pragma unroll
        for (int tj = 0; tj < 4; ++tj)
            bfr[tj] = *(const bf16x8*)&tB[(wc * 64 + tj * 16 + lrow) * 32 + kg * 8];
#pragma unroll
        for (int ti = 0; ti < 4; ++ti)
#pragma unroll
            for (int tj = 0; tj < 4; ++tj)
                acc[ti][tj] = __builtin_amdgcn_mfma_f32_16x16x32_bf16(
                    af[ti], bfr[tj], acc[ti][tj], 0, 0, 0);
    }

    // Epilogue: D[row = kg*4 + r][col = lane&15] per 16x16 tile.
    const int rbase = row0 + wr * 64;
    const int cbase = col0 + wc * 64 + lrow;
#pragma unroll
    for (int ti = 0; ti < 4; ++ti) {
#pragma unroll
        for (int r = 0; r < 4; ++r) {
            int row = rbase + ti * 16 + kg * 4 + r;
#pragma unroll
            for (int tj = 0; tj < 4; ++tj) {
                int col = cbase + tj * 16;
                if (col < N) {
                    long off = cOff + (long)row * ldc + col;
                    if (MODE == 0) Cb[off] = f2b(acc[ti][tj][r]);
                    else           atomicAdd(&Cf[off], acc[ti][tj][r]);
                }
            }
        }
    }
}

// ---------------------------------------------------------------------------
// Fused causal flash attention v2. One block = (b, head, 64 q-rows), 4 waves
// x 16 q-rows. K/V tiles (64 kv) double-buffered in LDS via global_load_lds
// with pre-swizzled global source (XOR granule ^ (row&7)); prefetch of tile
// j+1 is issued right after the barrier and overlaps compute of tile j.
// S^T = K@Q^T puts softmax lane-local + 2 shfl_xor; P round-trips through a
// per-wave swizzled LDS tile into PV MFMA A-fragments.
// qkv: [b*1024+t][3072] (q|k|v, rope applied).  vt: [b,h,d,s].  y: [b*T][C].
// ---------------------------------------------------------------------------
__global__ __launch_bounds__(256, 2)
void flash_k(const u16* __restrict__ qkv, const u16* __restrict__ vt,
             u16* __restrict__ y)
{
    __shared__ __align__(16) u16 tK[2][64 * 64];
    __shared__ __align__(16) u16 tV[2][64 * 64];
    __shared__ __align__(16) u16 tP[4][16 * 64];

    // bijective XCD swizzle over 512 blocks (512 % 8 == 0): 64 consecutive
    // blocks (4 heads' K/V ~1MB) per XCD -> K/V re-reads are L2 hits.
    const int bid0 = blockIdx.x;
    const int bid  = (bid0 & 7) * 64 + (bid0 >> 3);
    const int qt = bid & 15;
    const int hh = (bid >> 4) & 15;
    const int b  = bid >> 8;

    const int tid  = threadIdx.x;
    const int lane = tid & 63;
    const int w    = tid >> 6;           // wave 0..3
    const int l15  = lane & 15;
    const int kg   = lane >> 4;          // 0..3

    const int wq0 = qt * 64 + w * 16;    // wave's first q row
    u16* tPw = tP[w];

    // Q fragments in registers: qf[dk] = Q[wq0+l15][dk*32+kg*8 .. +8]
    bf16x8 qf[2];
#pragma unroll
    for (int dk = 0; dk < 2; ++dk)
        qf[dk] = *(const bf16x8*)(qkv
            + (size_t)(b * 1024 + wq0 + l15) * 3072 + hh * 64 + dk * 32 + kg * 8);

    f32x4 acc_o[4] = {};
    float mrun = -3e38f;
    float lrun = 0.f;

    const u16* Kg0 = qkv + (size_t)(b * 1024) * 3072 + 1024 + hh * 64;
    const u16* Vg0 = vt + (size_t)((b * 16 + hh) * 64) * 1024;

    // stage K-tile (rows=kv) and V^T-tile (rows=d) j into buffer bb;
    // global source pre-swizzled so LDS[row][gc] = global[row][gc^(row&7)].
    auto stage = [&](int bb, int j) {
#pragma unroll
        for (int i = 0; i < 2; ++i) {
            int chunk = i * 256 + tid;   // granule id 0..511
            int row = chunk >> 3, gc = chunk & 7;
            int sgc = gc ^ (row & 7);
            const u16* ga = Kg0 + (size_t)(j * 64 + row) * 3072 + sgc * 8;
            u16* la = tK[bb] + (size_t)(i * 256 + w * 64) * 8;  // wave-uniform
            __builtin_amdgcn_global_load_lds(
                (const __attribute__((address_space(1))) void*)ga,
                (__attribute__((address_space(3))) void*)la, 16, 0, 0);
            const u16* gb = Vg0 + (size_t)row * 1024 + j * 64 + sgc * 8;
            u16* lb = tV[bb] + (size_t)(i * 256 + w * 64) * 8;
            __builtin_amdgcn_global_load_lds(
                (const __attribute__((address_space(1))) void*)gb,
                (__attribute__((address_space(3))) void*)lb, 16, 0, 0);
        }
    };

    stage(0, 0);
    int cur = 0;

    for (int j = 0; j <= qt; ++j) {
        __syncthreads();                 // drains vmcnt: buf[cur] staged;
                                         // lgkm: prior reads of buf[cur^1] done
        if (j < qt) stage(cur ^ 1, j + 1);   // prefetch overlaps compute below

        const u16* K_ = tK[cur];
        const u16* V_ = tV[cur];

        // S^T[kv][q] = K @ Q^T : C/D col=q=l15, row=kv=kg*4+r (+16*kvt)
        f32x4 s[4] = {};
#pragma unroll
        for (int dk = 0; dk < 2; ++dk) {
            bf16x8 ak[4];
#pragma unroll
            for (int kvt = 0; kvt < 4; ++kvt) {
                int row = kvt * 16 + l15;
                int g = (dk * 4 + kg) ^ (row & 7);
                ak[kvt] = *(const bf16x8*)&K_[row * 64 + g * 8];
            }
#pragma unroll
            for (int kvt = 0; kvt < 4; ++kvt)
                s[kvt] = __builtin_amdgcn_mfma_f32_16x16x32_bf16(
                    ak[kvt], qf[dk], s[kvt], 0, 0, 0);
        }

        // scale + causal mask (diagonal tile only) + row max
        float tmax = -3e38f;
        const bool maskt = (j == qt);
#pragma unroll
        for (int kvt = 0; kvt < 4; ++kvt) {
            f32x4 v = s[kvt];
#pragma unroll
            for (int r = 0; r < 4; ++r) {
                float sv = v[r] * 0.125f;
                if (maskt && (j * 64 + kvt * 16 + kg * 4 + r > wq0 + l15))
                    sv = -3e38f;
                v[r] = sv;
                tmax = fmaxf(tmax, sv);
            }
            s[kvt] = v;
        }
        tmax = fmaxf(tmax, __shfl_xor(tmax, 16));
        tmax = fmaxf(tmax, __shfl_xor(tmax, 32));

        const float mn = fmaxf(mrun, tmax);
        const float sf = __expf(mrun - mn);   // first tile: exp(-inf) = 0
        mrun = mn;

        // rescale O rows q = kg*4 + ro: factor lives in lane (kg*4+ro)
#pragma unroll
        for (int ro = 0; ro < 4; ++ro) {
            float f = __shfl(sf, kg * 4 + ro);
#pragma unroll
            for (int dj = 0; dj < 4; ++dj)
                acc_o[dj][ro] *= f;
        }

        // exp, row-sum, pack bf16, write P[q][kv] to swizzled per-wave LDS
        float tsum = 0.f;
#pragma unroll
        for (int kvt = 0; kvt < 4; ++kvt) {
            f32x4 v = s[kvt];
            float p0 = __expf(v[0] - mn);
            float p1 = __expf(v[1] - mn);
            float p2 = __expf(v[2] - mn);
            float p3 = __expf(v[3] - mn);
            tsum += p0 + p1 + p2 + p3;
            ushort4 pk;
            pk.x = f2b(p0); pk.y = f2b(p1); pk.z = f2b(p2); pk.w = f2b(p3);
            int g = (kvt * 2 + (kg >> 1)) ^ (l15 & 7);
            *(ushort4*)&tPw[l15 * 64 + g * 8 + (kg & 1) * 4] = pk;
        }
        tsum += __shfl_xor(tsum, 16);
        tsum += __shfl_xor(tsum, 32);
        lrun = lrun * sf + tsum;

        // O += P @ V : A = P[q][kv] (own-wave LDS), B = V^T[d][kv]
#pragma unroll
        for (int ki = 0; ki < 2; ++ki) {
            bf16x8 ap, bv[4];
            {
                int g = (ki * 4 + kg) ^ (l15 & 7);
                ap = *(const bf16x8*)&tPw[l15 * 64 + g * 8];
            }
#pragma unroll
            for (int dj = 0; dj < 4; ++dj) {
                int row = dj * 16 + l15;
                int g = (ki * 4 + kg) ^ (row & 7);
                bv[dj] = *(const bf16x8*)&V_[row * 64 + g * 8];
            }
#pragma unroll
            for (int dj = 0; dj < 4; ++dj)
                acc_o[dj] = __builtin_amdgcn_mfma_f32_16x16x32_bf16(
                    ap, bv[dj], acc_o[dj], 0, 0, 0);
        }
        cur ^= 1;
    }

    // y[b, q, hh*64 + d] = O / l
    const float inv = 1.0f / lrun;
#pragma unroll
    for (int ro = 0; ro < 4; ++ro) {
        float iv = __shfl(inv, kg * 4 + ro);
        size_t rowo = (size_t)(b * 1024 + wq0 + kg * 4 + ro) * 1024
                    + hh * 64 + l15;
#pragma unroll
        for (int dj = 0; dj < 4; ++dj)
            y[rowo + dj * 16] = f2b(acc_o[dj][ro] * iv);
    }
}

// h[bt,c] = sum_f x[bt,f] * w_in[c,f]   (K=9, fp32 out)
__global__ void input_proj_k(const u16* __restrict__ x, const u16* __restrict__ w,
                             float* __restrict__ h)
{
    int idx = blockIdx.x * 256 + threadIdx.x;      // 2M
    int bt = idx >> 10, c = idx & 1023;
    float s = 0.f;
#pragma unroll
    for (int f = 0; f < 9; ++f) s += b2f(x[bt * 9 + f]) * b2f(w[c * 9 + f]);
    h[idx] = s;
}

// out[row,:] = h * rsqrt(mean(h^2)+eps) * g.  isFinal&&flag -> fp32 out.
// Vectorized: 256 threads x float4 == C=1024 exactly.
__global__ void rms_k(const float* __restrict__ h, const u16* __restrict__ g,
                      void* __restrict__ out, int isFinal,
                      const int* __restrict__ flag)
{
    __shared__ float red[8];
    const int row = blockIdx.x;
    const int tid = threadIdx.x;
    float4 v = ((const float4*)(h + (size_t)row * C_))[tid];
    float ss = v.x * v.x + v.y * v.y + v.z * v.z + v.w * v.w;
#pragma unroll
    for (int off = 32; off; off >>= 1) ss += __shfl_down(ss, off);
    int lane = tid & 63, wave = tid >> 6;
    if (lane == 0) red[wave] = ss;
    __syncthreads();
    if (tid == 0)
        red[4] = rsqrtf((red[0] + red[1] + red[2] + red[3]) / (float)C_ + EPS_);
    __syncthreads();
    const float r = red[4];
    ushort4 gv = ((const ushort4*)g)[tid];
    float o0 = v.x * r * b2f(gv.x);
    float o1 = v.y * r * b2f(gv.y);
    float o2 = v.z * r * b2f(gv.z);
    float o3 = v.w * r * b2f(gv.w);
    if (isFinal && flag[0]) {
        ((float4*)out)[(size_t)row * 256 + tid] = make_float4(o0, o1, o2, o3);
    } else {
        ushort4 o; o.x = f2b(o0); o.y = f2b(o1); o.z = f2b(o2); o.w = f2b(o3);
        ((ushort4*)out)[(size_t)row * 256 + tid] = o;
    }
}

// cos/sin table: tab[t*32+i] = {cos,sin}(t * 10000^(-i/32)), t<1024, i<32
__global__ void rope_tab_k(float2* __restrict__ tab)
{
    int idx = blockIdx.x * 256 + threadIdx.x;      // 32768
    int i = idx & 31;
    int t = idx >> 5;
    float invf = powf(10000.0f, -(float)i / 32.0f);
    float fr = (float)t * invf;
    tab[idx] = make_float2(cosf(fr), sinf(fr));
}

// RoPE in place on qkv[b,t,:]: q cols 0..1023, k cols 1024..2047 (ld 3072)
__global__ void rope_k(u16* __restrict__ qkv, const float2* __restrict__ tab)
{
    int idx = blockIdx.x * 256 + threadIdx.x;      // B*T*NH*32 = 1M
    int i = idx & 31;
    int hh = (idx >> 5) & 15;
    int t = (idx >> 9) & 1023;
    int b = idx >> 19;
    float2 cs = tab[(t << 5) + i];
    float cf = cs.x, sf = cs.y;

    size_t base = (size_t)(b * 1024 + t) * 3072 + hh * 64 + i;
    float x1 = b2f(qkv[base]), x2 = b2f(qkv[base + 32]);
    qkv[base]      = f2b(x1 * cf - x2 * sf);
    qkv[base + 32] = f2b(x2 * cf + x1 * sf);

    size_t kb = base + 1024;
    x1 = b2f(qkv[kb]); x2 = b2f(qkv[kb + 32]);
    qkv[kb]      = f2b(x1 * cf - x2 * sf);
    qkv[kb + 32] = f2b(x2 * cf + x1 * sf);
}

// vt[b,h,d,s] = qkv[b,s, 2048 + h*64 + d]  — LDS-tiled 64x64 transpose,
// coalesced vector access on both global sides.
__global__ void vtrans_k(const u16* __restrict__ qkv, u16* __restrict__ vt)
{
    __shared__ u16 tile[64][68];                   // pad 4 u16
    const int bz = blockIdx.x;                     // 512 = 2b * 16h * 16s-tiles
    const int s0 = (bz & 15) << 6;
    const int hh = (bz >> 4) & 15;
    const int b  = bz >> 8;
    const int tid = threadIdx.x;
#pragma unroll
    for (int it = 0; it < 2; ++it) {
        int id = it * 256 + tid;                   // 0..511
        int r  = id >> 3;                          // s-row within tile
        int cg = id & 7;                           // 8-wide d chunk
        const u16* src = qkv + (size_t)(b * 1024 + s0 + r) * 3072
                             + 2048 + hh * 64 + cg * 8;
        ushort4 a0 = *(const ushort4*)src;
        ushort4 a1 = *(const ushort4*)(src + 4);
        *(ushort4*)&tile[r][cg * 8]     = a0;
        *(ushort4*)&tile[r][cg * 8 + 4] = a1;
    }
    __syncthreads();
#pragma unroll
    for (int it = 0; it < 2; ++it) {
        int id = it * 256 + tid;
        int d  = id >> 3;                          // d row of output
        int cg = id & 7;                           // 8-wide s chunk
        ushort4 o0, o1;
        o0.x = tile[cg * 8 + 0][d]; o0.y = tile[cg * 8 + 1][d];
        o0.z = tile[cg * 8 + 2][d]; o0.w = tile[cg * 8 + 3][d];
        o1.x = tile[cg * 8 + 4][d]; o1.y = tile[cg * 8 + 5][d];
        o1.z = tile[cg * 8 + 6][d]; o1.w = tile[cg * 8 + 7][d];
        u16* dst = vt + (size_t)((b * 16 + hh) * 64 + d) * 1024 + s0 + cg * 8;
        *(ushort4*)dst       = o0;
        *(ushort4*)(dst + 4) = o1;
    }
}

// u1 = silu(u1) * u2   — ushort8 vectorized
__global__ void silu_mul_k(u16* __restrict__ u1, const u16* __restrict__ u2)
{
    size_t idx = (size_t)blockIdx.x * 256 + threadIdx.x;   // 720896 vec8
    u16x8 a8 = ((const u16x8*)u1)[idx];
    u16x8 b8 = ((const u16x8*)u2)[idx];
    u16x8 o;
#pragma unroll
    for (int j = 0; j < 8; ++j) {
        float a = b2f(a8[j]);
        float m = a / (1.f + __expf(-a));
        o[j] = f2b(m * b2f(b8[j]));
    }
    ((u16x8*)u1)[idx] = o;
}

// ---------------------------------------------------------------------------
static inline void launch_gemm(bool add, const u16* A, const u16* Bm, void* C,
                               int M, int N, int K, int lda, int ldb, int ldc,
                               int zdim, int nhDiv,
                               long sAb, long sAh, long sBb, long sBh,
                               long sCb, long sCh, int kSplit, hipStream_t stream)
{
    dim3 g((N + 127) / 128, M / 128, zdim);
    if (add)
        gemm_bt<1><<<g, 256, 0, stream>>>(A, Bm, nullptr, (float*)C,
            M, N, K, lda, ldb, ldc, nhDiv, sAb, sAh, sBb, sBh, sCb, sCh, kSplit);
    else
        gemm_bt<0><<<g, 256, 0, stream>>>(A, Bm, (u16*)C, nullptr,
            M, N, K, lda, ldb, ldc, nhDiv, sAb, sAh, sBb, sBh, sCb, sCh, kSplit);
}

static inline void launch_cvt(const void* src, u16* dst, long perV,
                              long dstStrideV, long dstOffV, int chunks,
                              const int* flag, hipStream_t stream)
{
    long bx = (perV + 255) / 256; if (bx > 512) bx = 512;
    dim3 g((unsigned)bx, (unsigned)chunks, 1);
    cvt_k<<<g, 256, 0, stream>>>(src, dst, perV, dstStrideV, dstOffV, flag);
}

extern "C" void kernel_launch(void* const* d_in, const int* in_sizes, int n_in,
                              void* d_out, int out_size, void* d_ws, size_t ws_size,
                              hipStream_t stream)
{
    char* w = (char*)d_ws;
    float* h   = (float*)w;                          // [0,8) MB fp32 residual
    u16* a     = (u16*)(w + (8u  << 20));            // [8,12)
    u16* qkv   = (u16*)(w + (12u << 20));            // [12,24)  [2048][3072]
    u16* vt    = (u16*)(w + (24u << 20));            // [24,28)
    u16* y     = (u16*)(w + (28u << 20));            // [28,32)
    u16* u1    = (u16*)(w + (32u << 20));            // [32,64) MLP buffers
    u16* u2    = u1 + (size_t)2048 * HFF_;

    // bf16 weight copies (relayout) above 64 MB — same footprint as before.
    size_t off = (size_t)64 << 20;
    u16* cx    = (u16*)(w + off); off += ((size_t)B_*T_*9*2   + 255) & ~(size_t)255;
    u16* cwin  = (u16*)(w + off); off += ((size_t)C_*9*2      + 255) & ~(size_t)255;
    u16* cwqkv = (u16*)(w + off); off += (size_t)L_*3072*1024*2;   // fused q|k|v
    u16* cwo   = (u16*)(w + off); off += (size_t)L_*C_*C_*2;
    u16* cw12  = (u16*)(w + off); off += (size_t)L_*2*HFF_*C_*2;   // fused w1|w2
    u16* cw3   = (u16*)(w + off); off += (size_t)L_*C_*HFF_*2;
    u16* cg1   = (u16*)(w + off); off += ((size_t)L_*C_*2 + 255) & ~(size_t)255;
    u16* cg2   = (u16*)(w + off); off += ((size_t)L_*C_*2 + 255) & ~(size_t)255;
    u16* cgf   = (u16*)(w + off); off += ((size_t)C_*2    + 255) & ~(size_t)255;
    int* flag  = (int*)(w + off); off += 256;
    float2* rtab = (float2*)(w + off);               // 1024*32*8 = 256 KB

    detect_k<<<1, 64, 0, stream>>>((const unsigned int*)d_in[0], flag);

    const long CCv  = (long)C_ * C_ / 4;        // 262144
    const long HCv  = (long)HFF_ * C_ / 4;      // 720896
    launch_cvt(d_in[0],  cx,    (long)B_*T_*9/4, 0, 0, 1, flag, stream);
    launch_cvt(d_in[1],  cwin,  (long)C_*9/4,    0, 0, 1, flag, stream);
    launch_cvt(d_in[2],  cwqkv, CCv,   3*CCv, 0,     L_, flag, stream);  // wq
    launch_cvt(d_in[3],  cwqkv, 2*CCv, 3*CCv, CCv,   L_, flag, stream);  // wkv
    launch_cvt(d_in[4],  cwo,   CCv,   CCv,   0,     L_, flag, stream);
    launch_cvt(d_in[5],  cw12,  HCv,   2*HCv, 0,     L_, flag, stream);  // w1
    launch_cvt(d_in[6],  cw12,  HCv,   2*HCv, HCv,   L_, flag, stream);  // w2
    launch_cvt(d_in[7],  cw3,   HCv,   HCv,   0,     L_, flag, stream);
    launch_cvt(d_in[8],  cg1,   (long)L_*C_/4, 0, 0, 1, flag, stream);
    launch_cvt(d_in[9],  cg2,   (long)L_*C_/4, 0, 0, 1, flag, stream);
    launch_cvt(d_in[10], cgf,   (long)C_/4,    0, 0, 1, flag, stream);

    rope_tab_k<<<128, 256, 0, stream>>>(rtab);

    input_proj_k<<<8192, 256, 0, stream>>>(cx, cwin, h);

    for (int l = 0; l < L_; ++l) {
        const u16* wqkv_l = cwqkv + (size_t)l * 3072 * 1024;
        const u16* wo_l   = cwo   + (size_t)l * C_ * C_;
        const u16* w12_l  = cw12  + (size_t)l * 2 * HFF_ * C_;
        const u16* w3_l   = cw3   + (size_t)l * C_ * HFF_;

        // --- attention ---
        rms_k<<<2048, 256, 0, stream>>>(h, cg1 + l * C_, a, 0, flag);
        // qkv[2048][3072] = a @ [wq|wk|wv]^T   (z=3 chunks of N=1024)
        launch_gemm(false, a, wqkv_l, qkv, 2048, 1024, 1024, 1024, 1024, 3072,
                    3, 3, 0, 0, 0, (long)C_*C_, 0, 1024, 1, stream);
        rope_k<<<4096, 256, 0, stream>>>(qkv, rtab);
        vtrans_k<<<512, 256, 0, stream>>>(qkv, vt);
        // fused flash attention -> y
        flash_k<<<512, 256, 0, stream>>>(qkv, vt, y);
        // h += y @ wo^T   (split-K x4)
        launch_gemm(true, y, wo_l, h, 2048, 1024, 1024, 1024, 1024, 1024,
                    4, 1, 0, 0, 0, 0, 0, 0, 4, stream);

        // --- MLP ---
        rms_k<<<2048, 256, 0, stream>>>(h, cg2 + l * C_, a, 0, flag);
        // [u1|u2] = a @ [w1|w2]^T   (z=2 chunks of N=2816)
        launch_gemm(false, a, w12_l, u1, 2048, HFF_, 1024, 1024, 1024, HFF_,
                    2, 2, 0, 0, 0, (long)HFF_*C_, 0, (long)2048*HFF_, 1, stream);
        silu_mul_k<<<2816, 256, 0, stream>>>(u1, u2);
        // h += u1 @ w3^T   (split-K x4, K=2816 -> 704 per slice)
        launch_gemm(true, u1, w3_l, h, 2048, 1024, HFF_, HFF_, HFF_, 1024,
                    4, 1, 0, 0, 0, 0, 0, 0, 4, stream);
    }

    rms_k<<<2048, 256, 0, stream>>>(h, cgf, d_out, 1, flag);
}

// Round 4
// 962.990 us; speedup vs baseline: 1.3695x; 1.0225x over previous
//
#include <hip/hip_runtime.h>
#include <hip/hip_bf16.h>

// LagLlama forward. fp32/bf16 input autodetect -> bf16 copies in ws.
// fp32 residual stream. Round 9 = R8 + atomic-free split-K (partials + fused
// reduce in rms) + RoPE fused into qkv GEMM epilogue.
// B=2 T=1024 C=1024 NH=16 DH=64 L=4 HFF=2816

#define B_   2
#define T_   1024
#define C_   1024
#define NH_  16
#define DH_  64
#define L_   4
#define HFF_ 2816
#define EPS_ 1e-5f

typedef unsigned short u16;
typedef short bf16x8 __attribute__((ext_vector_type(8)));
typedef unsigned short u16x8 __attribute__((ext_vector_type(8)));
typedef float f32x4 __attribute__((ext_vector_type(4)));

__device__ __forceinline__ float b2f(u16 u) {
    union { unsigned int i; float f; } v; v.i = ((unsigned int)u) << 16; return v.f;
}
__device__ __forceinline__ u16 f2b(float f) {
    union { unsigned int i; float f; } v; v.f = f;
    unsigned int r = (v.i + 0x7fff + ((v.i >> 16) & 1)) >> 16;
    return (u16)r;
}

// flag: 0 = inputs are bf16, 1 = inputs are fp32 (detected from x's raw bits)
__global__ void detect_k(const unsigned int* __restrict__ xw, int* __restrict__ flag)
{
    int tid = threadIdx.x;
    int cnt = 0;
#pragma unroll
    for (int i = 0; i < 4; ++i) {
        unsigned int w = xw[tid * 4 + i];
        unsigned int e = (w >> 7) & 0xFF;
        if (e >= 0x70 && e <= 0x87) cnt++;
    }
#pragma unroll
    for (int off = 32; off; off >>= 1) cnt += __shfl_down(cnt, off);
    if (tid == 0) flag[0] = (cnt > 128) ? 0 : 1;
}

// Relayout+convert: for chunk y (blockIdx.y), vec4-index i:
//   dst4[y*dstStrideV + dstOffV + i] = cvt(src4[y*perV + i])
__global__ void cvt_k(const void* __restrict__ src, u16* __restrict__ dst,
                      long perV, long dstStrideV, long dstOffV,
                      const int* __restrict__ flag)
{
    const int f = flag[0];
    long y = blockIdx.y;
    long i = (long)blockIdx.x * 256 + threadIdx.x;
    long stride = (long)gridDim.x * 256;
    for (; i < perV; i += stride) {
        long so = y * perV + i;
        long dj = y * dstStrideV + dstOffV + i;
        ushort4 o;
        if (f) {
            float4 v = ((const float4*)src)[so];
            o.x = f2b(v.x); o.y = f2b(v.y); o.z = f2b(v.z); o.w = f2b(v.w);
        } else {
            o = ((const ushort4*)src)[so];
        }
        ((ushort4*)dst)[dj] = o;
    }
}

// ---------------------------------------------------------------------------
// Batched GEMM: C[m,n] = sum_k A[m,k] * B[n,k]   (A: MxK lda, B: NxK ldb)
// MODE 0: write bf16 to Cb; z = batch (bb=z/nhDiv, hh=z%nhDiv), offsets
//         bb*s?b + hh*s?h (elements). ropeMode: apply RoPE in epilogue for
//         hh<2 (q,k chunks of the fused qkv GEMM) using table rt.
// MODE 1: z = K-slice (kSplit slices); slices 0..kSplit-2 store fp32 partials
//         to Pf[z*M*ldc + off]; slice kSplit-1 does non-atomic Cf[off] += acc
//         (exactly one writer per cell). NO atomics.
// M % 128 == 0; K (or K/kSplit) % 32 == 0.
// Bijective XCD swizzle (m204) for L2 locality.
// ---------------------------------------------------------------------------
template<int MODE>
__global__ __launch_bounds__(256, 2)
void gemm_bt(const u16* __restrict__ A, const u16* __restrict__ Bm,
             u16* __restrict__ Cb, float* __restrict__ Cf,
             float* __restrict__ Pf,
             int M, int N, int K, int lda, int ldb, int ldc,
             int nhDiv, long sAb, long sAh, long sBb, long sBh,
             long sCb, long sCh, int kSplit, int ropeMode,
             const float2* __restrict__ rt)
{
    __shared__ __align__(16) u16 tA[128 * 32];
    __shared__ __align__(16) u16 tB[128 * 32];

    // --- XCD-aware bijective remap of the linear workgroup id ---
    const unsigned nx = gridDim.x, ny = gridDim.y;
    const unsigned nwg = nx * ny * gridDim.z;
    const unsigned lin = blockIdx.x + nx * (blockIdx.y + ny * blockIdx.z);
    const unsigned qd = nwg >> 3, rm = nwg & 7;
    const unsigned xcd = lin & 7, pos = lin >> 3;
    const unsigned wg = (xcd < rm ? xcd * (qd + 1)
                                  : rm * (qd + 1) + (xcd - rm) * qd) + pos;
    const unsigned bx = wg % nx;
    const unsigned tmp = wg / nx;
    const unsigned by = tmp % ny;
    const unsigned bz = tmp / ny;

    const int z = (int)bz;
    int kBeg = 0, kEnd = K;
    const u16* Ab = A;
    const u16* Bb = Bm;
    long cOff = 0;
    int hh_s = 0;
    if (MODE == 1) {
        int ks = K / kSplit;
        kBeg = z * ks; kEnd = kBeg + ks;
    } else {
        int bb = z / nhDiv;
        int hh = z - bb * nhDiv;
        Ab += bb * sAb + hh * sAh;
        Bb += bb * sBb + hh * sBh;
        cOff = bb * sCb + hh * sCh;
        hh_s = hh;
    }

    const int row0 = by * 128;
    const int col0 = bx * 128;

    const int tid  = threadIdx.x;
    const int lane = tid & 63;
    const int wave = tid >> 6;
    const int wr = wave >> 1, wc = wave & 1;   // 2x2 waves of 64x64
    const int lrow = lane & 15;
    const int kg   = lane >> 4;

    f32x4 acc[4][4] = {};

    for (int k0 = kBeg; k0 < kEnd; k0 += 32) {
        __syncthreads();   // prior iter's LDS reads done before overwrite
#pragma unroll
        for (int i = 0; i < 2; ++i) {          // A tile: 512 x 16B chunks
            int chunk = i * 256 + tid;
            int r = chunk >> 2, cg = chunk & 3;
            const u16* ga = Ab + (long)(row0 + r) * lda + (k0 + cg * 8);
            u16* la = tA + (size_t)(i * 256 + wave * 64) * 8;  // wave-uniform
            __builtin_amdgcn_global_load_lds(
                (const __attribute__((address_space(1))) void*)ga,
                (__attribute__((address_space(3))) void*)la, 16, 0, 0);
        }
#pragma unroll
        for (int i = 0; i < 2; ++i) {          // B tile
            int chunk = i * 256 + tid;
            int r = chunk >> 2, cg = chunk & 3;
            int rB = col0 + r; if (rB > N - 1) rB = N - 1;   // N-tail clamp
            const u16* gb = Bb + (long)rB * ldb + (k0 + cg * 8);
            u16* lb = tB + (size_t)(i * 256 + wave * 64) * 8;
            __builtin_amdgcn_global_load_lds(
                (const __attribute__((address_space(1))) void*)gb,
                (__attribute__((address_space(3))) void*)lb, 16, 0, 0);
        }
        __syncthreads();

        bf16x8 af[4], bfr[4];
#pragma unroll
        for (int ti = 0; ti < 4; ++ti)
            af[ti] = *(const bf16x8*)&tA[(wr * 64 + ti * 16 + lrow) * 32 + kg * 8];
#pragma unroll
        for (int tj = 0; tj < 4; ++tj)
            bfr[tj] = *(const bf16x8*)&tB[(wc * 64 + tj * 16 + lrow) * 32 + kg * 8];
#pragma unroll
        for (int ti = 0; ti < 4; ++ti)
#pragma unroll
            for (int tj = 0; tj < 4; ++tj)
                acc[ti][tj] = __builtin_amdgcn_mfma_f32_16x16x32_bf16(
                    af[ti], bfr[tj], acc[ti][tj], 0, 0, 0);
    }

    // Epilogue: D[row = kg*4 + r][col = lane&15] per 16x16 tile.
    const int rbase = row0 + wr * 64;
    const int cbase = col0 + wc * 64 + lrow;

    if (MODE == 0) {
        const bool doRope = ropeMode && (hh_s < 2);
#pragma unroll
        for (int ti = 0; ti < 4; ++ti) {
#pragma unroll
            for (int r = 0; r < 4; ++r) {
                int row = rbase + ti * 16 + kg * 4 + r;
                float o0 = acc[ti][0][r], o1 = acc[ti][1][r];
                float o2 = acc[ti][2][r], o3 = acc[ti][3][r];
                if (doRope) {
                    int t = row & 1023;
                    float2 c0 = rt[t * 32 + lrow];         // i = lrow
                    float2 c1 = rt[t * 32 + 16 + lrow];    // i = 16 + lrow
                    float n0 = o0 * c0.x - o2 * c0.y;
                    float n2 = o2 * c0.x + o0 * c0.y;
                    float n1 = o1 * c1.x - o3 * c1.y;
                    float n3 = o3 * c1.x + o1 * c1.y;
                    o0 = n0; o1 = n1; o2 = n2; o3 = n3;
                }
                float ov[4] = { o0, o1, o2, o3 };
#pragma unroll
                for (int tj = 0; tj < 4; ++tj) {
                    int col = cbase + tj * 16;
                    if (col < N)
                        Cb[cOff + (long)row * ldc + col] = f2b(ov[tj]);
                }
            }
        }
    } else {
        const size_t pstr = (size_t)M * ldc;
        const bool last = (z == kSplit - 1);
#pragma unroll
        for (int ti = 0; ti < 4; ++ti) {
#pragma unroll
            for (int r = 0; r < 4; ++r) {
                int row = rbase + ti * 16 + kg * 4 + r;
#pragma unroll
                for (int tj = 0; tj < 4; ++tj) {
                    int col = cbase + tj * 16;
                    long off = (long)row * ldc + col;
                    if (last) Cf[off] += acc[ti][tj][r];   // single writer/cell
                    else      Pf[(size_t)z * pstr + off] = acc[ti][tj][r];
                }
            }
        }
    }
}

// ---------------------------------------------------------------------------
// Fused causal flash attention. One block = (b, head, 64 q-rows), 4 waves x
// 16 q-rows. K/V tiles double-buffered in LDS via global_load_lds with
// pre-swizzled global source; prefetch of tile j+1 overlaps compute of j.
// S^T = K@Q^T puts softmax lane-local + 2 shfl_xor; P round-trips through a
// per-wave swizzled LDS tile into PV MFMA A-fragments.
// ---------------------------------------------------------------------------
__global__ __launch_bounds__(256, 2)
void flash_k(const u16* __restrict__ qkv, const u16* __restrict__ vt,
             u16* __restrict__ y)
{
    __shared__ __align__(16) u16 tK[2][64 * 64];
    __shared__ __align__(16) u16 tV[2][64 * 64];
    __shared__ __align__(16) u16 tP[4][16 * 64];

    const int bid0 = blockIdx.x;
    const int bid  = (bid0 & 7) * 64 + (bid0 >> 3);   // XCD swizzle (512%8==0)
    const int qt = bid & 15;
    const int hh = (bid >> 4) & 15;
    const int b  = bid >> 8;

    const int tid  = threadIdx.x;
    const int lane = tid & 63;
    const int w    = tid >> 6;           // wave 0..3
    const int l15  = lane & 15;
    const int kg   = lane >> 4;          // 0..3

    const int wq0 = qt * 64 + w * 16;    // wave's first q row
    u16* tPw = tP[w];

    bf16x8 qf[2];
#pragma unroll
    for (int dk = 0; dk < 2; ++dk)
        qf[dk] = *(const bf16x8*)(qkv
            + (size_t)(b * 1024 + wq0 + l15) * 3072 + hh * 64 + dk * 32 + kg * 8);

    f32x4 acc_o[4] = {};
    float mrun = -3e38f;
    float lrun = 0.f;

    const u16* Kg0 = qkv + (size_t)(b * 1024) * 3072 + 1024 + hh * 64;
    const u16* Vg0 = vt + (size_t)((b * 16 + hh) * 64) * 1024;

    auto stage = [&](int bb, int j) {
#pragma unroll
        for (int i = 0; i < 2; ++i) {
            int chunk = i * 256 + tid;   // granule id 0..511
            int row = chunk >> 3, gc = chunk & 7;
            int sgc = gc ^ (row & 7);
            const u16* ga = Kg0 + (size_t)(j * 64 + row) * 3072 + sgc * 8;
            u16* la = tK[bb] + (size_t)(i * 256 + w * 64) * 8;  // wave-uniform
            __builtin_amdgcn_global_load_lds(
                (const __attribute__((address_space(1))) void*)ga,
                (__attribute__((address_space(3))) void*)la, 16, 0, 0);
            const u16* gb = Vg0 + (size_t)row * 1024 + j * 64 + sgc * 8;
            u16* lb = tV[bb] + (size_t)(i * 256 + w * 64) * 8;
            __builtin_amdgcn_global_load_lds(
                (const __attribute__((address_space(1))) void*)gb,
                (__attribute__((address_space(3))) void*)lb, 16, 0, 0);
        }
    };

    stage(0, 0);
    int cur = 0;

    for (int j = 0; j <= qt; ++j) {
        __syncthreads();
        if (j < qt) stage(cur ^ 1, j + 1);   // prefetch overlaps compute

        const u16* K_ = tK[cur];
        const u16* V_ = tV[cur];

        f32x4 s[4] = {};
#pragma unroll
        for (int dk = 0; dk < 2; ++dk) {
            bf16x8 ak[4];
#pragma unroll
            for (int kvt = 0; kvt < 4; ++kvt) {
                int row = kvt * 16 + l15;
                int g = (dk * 4 + kg) ^ (row & 7);
                ak[kvt] = *(const bf16x8*)&K_[row * 64 + g * 8];
            }
#pragma unroll
            for (int kvt = 0; kvt < 4; ++kvt)
                s[kvt] = __builtin_amdgcn_mfma_f32_16x16x32_bf16(
                    ak[kvt], qf[dk], s[kvt], 0, 0, 0);
        }

        float tmax = -3e38f;
        const bool maskt = (j == qt);
#pragma unroll
        for (int kvt = 0; kvt < 4; ++kvt) {
            f32x4 v = s[kvt];
#pragma unroll
            for (int r = 0; r < 4; ++r) {
                float sv = v[r] * 0.125f;
                if (maskt && (j * 64 + kvt * 16 + kg * 4 + r > wq0 + l15))
                    sv = -3e38f;
                v[r] = sv;
                tmax = fmaxf(tmax, sv);
            }
            s[kvt] = v;
        }
        tmax = fmaxf(tmax, __shfl_xor(tmax, 16));
        tmax = fmaxf(tmax, __shfl_xor(tmax, 32));

        const float mn = fmaxf(mrun, tmax);
        const float sf = __expf(mrun - mn);
        mrun = mn;

#pragma unroll
        for (int ro = 0; ro < 4; ++ro) {
            float f = __shfl(sf, kg * 4 + ro);
#pragma unroll
            for (int dj = 0; dj < 4; ++dj)
                acc_o[dj][ro] *= f;
        }

        float tsum = 0.f;
#pragma unroll
        for (int kvt = 0; kvt < 4; ++kvt) {
            f32x4 v = s[kvt];
            float p0 = __expf(v[0] - mn);
            float p1 = __expf(v[1] - mn);
            float p2 = __expf(v[2] - mn);
            float p3 = __expf(v[3] - mn);
            tsum += p0 + p1 + p2 + p3;
            ushort4 pk;
            pk.x = f2b(p0); pk.y = f2b(p1); pk.z = f2b(p2); pk.w = f2b(p3);
            int g = (kvt * 2 + (kg >> 1)) ^ (l15 & 7);
            *(ushort4*)&tPw[l15 * 64 + g * 8 + (kg & 1) * 4] = pk;
        }
        tsum += __shfl_xor(tsum, 16);
        tsum += __shfl_xor(tsum, 32);
        lrun = lrun * sf + tsum;

#pragma unroll
        for (int ki = 0; ki < 2; ++ki) {
            bf16x8 ap, bv[4];
            {
                int g = (ki * 4 + kg) ^ (l15 & 7);
                ap = *(const bf16x8*)&tPw[l15 * 64 + g * 8];
            }
#pragma unroll
            for (int dj = 0; dj < 4; ++dj) {
                int row = dj * 16 + l15;
                int g = (ki * 4 + kg) ^ (row & 7);
                bv[dj] = *(const bf16x8*)&V_[row * 64 + g * 8];
            }
#pragma unroll
            for (int dj = 0; dj < 4; ++dj)
                acc_o[dj] = __builtin_amdgcn_mfma_f32_16x16x32_bf16(
                    ap, bv[dj], acc_o[dj], 0, 0, 0);
        }
        cur ^= 1;
    }

    const float inv = 1.0f / lrun;
#pragma unroll
    for (int ro = 0; ro < 4; ++ro) {
        float iv = __shfl(inv, kg * 4 + ro);
        size_t rowo = (size_t)(b * 1024 + wq0 + kg * 4 + ro) * 1024
                    + hh * 64 + l15;
#pragma unroll
        for (int dj = 0; dj < 4; ++dj)
            y[rowo + dj * 16] = f2b(acc_o[dj][ro] * iv);
    }
}

// h[bt,c] = sum_f x[bt,f] * w_in[c,f]   (K=9, fp32 out)
__global__ void input_proj_k(const u16* __restrict__ x, const u16* __restrict__ w,
                             float* __restrict__ h)
{
    int idx = blockIdx.x * 256 + threadIdx.x;      // 2M
    int bt = idx >> 10, c = idx & 1023;
    float s = 0.f;
#pragma unroll
    for (int f = 0; f < 9; ++f) s += b2f(x[bt * 9 + f]) * b2f(w[c * 9 + f]);
    h[idx] = s;
}

// Fused residual-reduce + RMSNorm.
// v = h[row] + sum_{p<nP} P[p][row];  if (hOut) hOut[row] = v;
// out[row] = v * rsqrt(mean(v^2)+eps) * g.   isFinal&&flag -> fp32 out.
__global__ void rms_k(const float* __restrict__ h, const float* __restrict__ P,
                      int nP, const u16* __restrict__ g,
                      void* __restrict__ out, float* __restrict__ hOut,
                      int isFinal, const int* __restrict__ flag)
{
    __shared__ float red[8];
    const int row = blockIdx.x;
    const int tid = threadIdx.x;
    float4 v = ((const float4*)(h + (size_t)row * C_))[tid];
    for (int p = 0; p < nP; ++p) {
        float4 pv = ((const float4*)P)[(size_t)p * 524288 + row * 256 + tid];
        v.x += pv.x; v.y += pv.y; v.z += pv.z; v.w += pv.w;
    }
    if (hOut) ((float4*)hOut)[(size_t)row * 256 + tid] = v;
    float ss = v.x * v.x + v.y * v.y + v.z * v.z + v.w * v.w;
#pragma unroll
    for (int off = 32; off; off >>= 1) ss += __shfl_down(ss, off);
    int lane = tid & 63, wave = tid >> 6;
    if (lane == 0) red[wave] = ss;
    __syncthreads();
    if (tid == 0)
        red[4] = rsqrtf((red[0] + red[1] + red[2] + red[3]) / (float)C_ + EPS_);
    __syncthreads();
    const float r = red[4];
    ushort4 gv = ((const ushort4*)g)[tid];
    float o0 = v.x * r * b2f(gv.x);
    float o1 = v.y * r * b2f(gv.y);
    float o2 = v.z * r * b2f(gv.z);
    float o3 = v.w * r * b2f(gv.w);
    if (isFinal && flag[0]) {
        ((float4*)out)[(size_t)row * 256 + tid] = make_float4(o0, o1, o2, o3);
    } else {
        ushort4 o; o.x = f2b(o0); o.y = f2b(o1); o.z = f2b(o2); o.w = f2b(o3);
        ((ushort4*)out)[(size_t)row * 256 + tid] = o;
    }
}

// cos/sin table: tab[t*32+i] = {cos,sin}(t * 10000^(-i/32)), t<1024, i<32
__global__ void rope_tab_k(float2* __restrict__ tab)
{
    int idx = blockIdx.x * 256 + threadIdx.x;      // 32768
    int i = idx & 31;
    int t = idx >> 5;
    float invf = powf(10000.0f, -(float)i / 32.0f);
    float fr = (float)t * invf;
    tab[idx] = make_float2(cosf(fr), sinf(fr));
}

// vt[b,h,d,s] = qkv[b,s, 2048 + h*64 + d]  — LDS-tiled 64x64 transpose.
__global__ void vtrans_k(const u16* __restrict__ qkv, u16* __restrict__ vt)
{
    __shared__ u16 tile[64][68];                   // pad 4 u16
    const int bz = blockIdx.x;                     // 512 = 2b * 16h * 16s-tiles
    const int s0 = (bz & 15) << 6;
    const int hh = (bz >> 4) & 15;
    const int b  = bz >> 8;
    const int tid = threadIdx.x;
#pragma unroll
    for (int it = 0; it < 2; ++it) {
        int id = it * 256 + tid;                   // 0..511
        int r  = id >> 3;                          // s-row within tile
        int cg = id & 7;                           // 8-wide d chunk
        const u16* src = qkv + (size_t)(b * 1024 + s0 + r) * 3072
                             + 2048 + hh * 64 + cg * 8;
        ushort4 a0 = *(const ushort4*)src;
        ushort4 a1 = *(const ushort4*)(src + 4);
        *(ushort4*)&tile[r][cg * 8]     = a0;
        *(ushort4*)&tile[r][cg * 8 + 4] = a1;
    }
    __syncthreads();
#pragma unroll
    for (int it = 0; it < 2; ++it) {
        int id = it * 256 + tid;
        int d  = id >> 3;                          // d row of output
        int cg = id & 7;                           // 8-wide s chunk
        ushort4 o0, o1;
        o0.x = tile[cg * 8 + 0][d]; o0.y = tile[cg * 8 + 1][d];
        o0.z = tile[cg * 8 + 2][d]; o0.w = tile[cg * 8 + 3][d];
        o1.x = tile[cg * 8 + 4][d]; o1.y = tile[cg * 8 + 5][d];
        o1.z = tile[cg * 8 + 6][d]; o1.w = tile[cg * 8 + 7][d];
        u16* dst = vt + (size_t)((b * 16 + hh) * 64 + d) * 1024 + s0 + cg * 8;
        *(ushort4*)dst       = o0;
        *(ushort4*)(dst + 4) = o1;
    }
}

// u1 = silu(u1) * u2   — ushort8 vectorized
__global__ void silu_mul_k(u16* __restrict__ u1, const u16* __restrict__ u2)
{
    size_t idx = (size_t)blockIdx.x * 256 + threadIdx.x;   // 720896 vec8
    u16x8 a8 = ((const u16x8*)u1)[idx];
    u16x8 b8 = ((const u16x8*)u2)[idx];
    u16x8 o;
#pragma unroll
    for (int j = 0; j < 8; ++j) {
        float a = b2f(a8[j]);
        float m = a / (1.f + __expf(-a));
        o[j] = f2b(m * b2f(b8[j]));
    }
    ((u16x8*)u1)[idx] = o;
}

// ---------------------------------------------------------------------------
static inline void launch_gemm(bool add, const u16* A, const u16* Bm, void* C,
                               float* Pf,
                               int M, int N, int K, int lda, int ldb, int ldc,
                               int zdim, int nhDiv,
                               long sAb, long sAh, long sBb, long sBh,
                               long sCb, long sCh, int kSplit, int ropeMode,
                               const float2* rt, hipStream_t stream)
{
    dim3 g((N + 127) / 128, M / 128, zdim);
    if (add)
        gemm_bt<1><<<g, 256, 0, stream>>>(A, Bm, nullptr, (float*)C, Pf,
            M, N, K, lda, ldb, ldc, nhDiv, sAb, sAh, sBb, sBh, sCb, sCh,
            kSplit, 0, nullptr);
    else
        gemm_bt<0><<<g, 256, 0, stream>>>(A, Bm, (u16*)C, nullptr, nullptr,
            M, N, K, lda, ldb, ldc, nhDiv, sAb, sAh, sBb, sBh, sCb, sCh,
            kSplit, ropeMode, rt);
}

static inline void launch_cvt(const void* src, u16* dst, long perV,
                              long dstStrideV, long dstOffV, int chunks,
                              const int* flag, hipStream_t stream)
{
    long bx = (perV + 255) / 256; if (bx > 512) bx = 512;
    dim3 g((unsigned)bx, (unsigned)chunks, 1);
    cvt_k<<<g, 256, 0, stream>>>(src, dst, perV, dstStrideV, dstOffV, flag);
}

extern "C" void kernel_launch(void* const* d_in, const int* in_sizes, int n_in,
                              void* d_out, int out_size, void* d_ws, size_t ws_size,
                              hipStream_t stream)
{
    char* w = (char*)d_ws;
    // Layout (lifetimes verified against P usage):
    //   [0,8)    h fp32 residual
    //   [8,32)   P: 3 fp32 split-K partial slices (8 MB each); also overlaps
    //            qkv [12,24) and vt [24,28) whose lifetimes don't intersect P's
    //   [32,55)  u1|u2 MLP buffers
    //   [56,60)  y attention output
    //   [60,64)  a (rms output, bf16)
    float* h   = (float*)w;
    float* P   = (float*)(w + (8u  << 20));
    u16* qkv   = (u16*)(w + (12u << 20));
    u16* vt    = (u16*)(w + (24u << 20));
    u16* u1    = (u16*)(w + (32u << 20));
    u16* u2    = u1 + (size_t)2048 * HFF_;
    u16* y     = (u16*)(w + (56u << 20));
    u16* a     = (u16*)(w + (60u << 20));

    // bf16 weight copies (relayout) above 64 MB — same footprint as before.
    size_t off = (size_t)64 << 20;
    u16* cx    = (u16*)(w + off); off += ((size_t)B_*T_*9*2   + 255) & ~(size_t)255;
    u16* cwin  = (u16*)(w + off); off += ((size_t)C_*9*2      + 255) & ~(size_t)255;
    u16* cwqkv = (u16*)(w + off); off += (size_t)L_*3072*1024*2;   // fused q|k|v
    u16* cwo   = (u16*)(w + off); off += (size_t)L_*C_*C_*2;
    u16* cw12  = (u16*)(w + off); off += (size_t)L_*2*HFF_*C_*2;   // fused w1|w2
    u16* cw3   = (u16*)(w + off); off += (size_t)L_*C_*HFF_*2;
    u16* cg1   = (u16*)(w + off); off += ((size_t)L_*C_*2 + 255) & ~(size_t)255;
    u16* cg2   = (u16*)(w + off); off += ((size_t)L_*C_*2 + 255) & ~(size_t)255;
    u16* cgf   = (u16*)(w + off); off += ((size_t)C_*2    + 255) & ~(size_t)255;
    int* flag  = (int*)(w + off); off += 256;
    float2* rtab = (float2*)(w + off);               // 1024*32*8 = 256 KB

    detect_k<<<1, 64, 0, stream>>>((const unsigned int*)d_in[0], flag);

    const long CCv  = (long)C_ * C_ / 4;        // 262144
    const long HCv  = (long)HFF_ * C_ / 4;      // 720896
    launch_cvt(d_in[0],  cx,    (long)B_*T_*9/4, 0, 0, 1, flag, stream);
    launch_cvt(d_in[1],  cwin,  (long)C_*9/4,    0, 0, 1, flag, stream);
    launch_cvt(d_in[2],  cwqkv, CCv,   3*CCv, 0,     L_, flag, stream);  // wq
    launch_cvt(d_in[3],  cwqkv, 2*CCv, 3*CCv, CCv,   L_, flag, stream);  // wkv
    launch_cvt(d_in[4],  cwo,   CCv,   CCv,   0,     L_, flag, stream);
    launch_cvt(d_in[5],  cw12,  HCv,   2*HCv, 0,     L_, flag, stream);  // w1
    launch_cvt(d_in[6],  cw12,  HCv,   2*HCv, HCv,   L_, flag, stream);  // w2
    launch_cvt(d_in[7],  cw3,   HCv,   HCv,   0,     L_, flag, stream);
    launch_cvt(d_in[8],  cg1,   (long)L_*C_/4, 0, 0, 1, flag, stream);
    launch_cvt(d_in[9],  cg2,   (long)L_*C_/4, 0, 0, 1, flag, stream);
    launch_cvt(d_in[10], cgf,   (long)C_/4,    0, 0, 1, flag, stream);

    rope_tab_k<<<128, 256, 0, stream>>>(rtab);

    input_proj_k<<<8192, 256, 0, stream>>>(cx, cwin, h);

    for (int l = 0; l < L_; ++l) {
        const u16* wqkv_l = cwqkv + (size_t)l * 3072 * 1024;
        const u16* wo_l   = cwo   + (size_t)l * C_ * C_;
        const u16* w12_l  = cw12  + (size_t)l * 2 * HFF_ * C_;
        const u16* w3_l   = cw3   + (size_t)l * C_ * HFF_;

        // --- attention ---
        // rms1: layer 0 plain; layers >0 fold previous w3 partials into h.
        if (l == 0)
            rms_k<<<2048, 256, 0, stream>>>(h, nullptr, 0, cg1, a, nullptr, 0, flag);
        else
            rms_k<<<2048, 256, 0, stream>>>(h, P, 3, cg1 + l * C_, a, h, 0, flag);
        // qkv[2048][3072] = a @ [wq|wk|wv]^T  (z=3 chunks; RoPE fused for q,k)
        launch_gemm(false, a, wqkv_l, qkv, nullptr,
                    2048, 1024, 1024, 1024, 1024, 3072,
                    3, 3, 0, 0, 0, (long)C_*C_, 0, 1024, 1, 1, rtab, stream);
        vtrans_k<<<512, 256, 0, stream>>>(qkv, vt);
        flash_k<<<512, 256, 0, stream>>>(qkv, vt, y);
        // wo split-K x4: slices 0-2 -> P, slice 3 RMW h += acc
        launch_gemm(true, y, wo_l, h, P, 2048, 1024, 1024, 1024, 1024, 1024,
                    4, 1, 0, 0, 0, 0, 0, 0, 4, 0, nullptr, stream);

        // --- MLP ---
        rms_k<<<2048, 256, 0, stream>>>(h, P, 3, cg2 + l * C_, a, h, 0, flag);
        // [u1|u2] = a @ [w1|w2]^T   (z=2 chunks of N=2816)
        launch_gemm(false, a, w12_l, u1, nullptr,
                    2048, HFF_, 1024, 1024, 1024, HFF_,
                    2, 2, 0, 0, 0, (long)HFF_*C_, 0, (long)2048*HFF_, 1, 0,
                    nullptr, stream);
        silu_mul_k<<<2816, 256, 0, stream>>>(u1, u2);
        // w3 split-K x4 (K=2816 -> 704/slice): slices 0-2 -> P, slice 3 RMW h
        launch_gemm(true, u1, w3_l, h, P, 2048, 1024, HFF_, HFF_, HFF_, 1024,
                    4, 1, 0, 0, 0, 0, 0, 0, 4, 0, nullptr, stream);
    }

    // final rms folds last w3 partials (no h write-back needed)
    rms_k<<<2048, 256, 0, stream>>>(h, P, 3, cgf, d_out, nullptr, 1, flag);
}

// Round 7
// 960.625 us; speedup vs baseline: 1.3728x; 1.0025x over previous
//
#include <hip/hip_runtime.h>
#include <hip/hip_bf16.h>

// LagLlama forward. fp32/bf16 input autodetect -> bf16 copies in ws.
// fp32 residual stream. Round 12 = R11 with w3 ldb fix (2816, not 5632).
// gemm_bt 1-deep prefetch dbuf (T3-min), single-launch qkv (N=3072) /
// w12 (N=5632 interleaved), fused weight-cvt kernel, flash longest-first.
// B=2 T=1024 C=1024 NH=16 DH=64 L=4 HFF=2816

#define B_   2
#define T_   1024
#define C_   1024
#define NH_  16
#define DH_  64
#define L_   4
#define HFF_ 2816
#define EPS_ 1e-5f

typedef unsigned short u16;
typedef short bf16x8 __attribute__((ext_vector_type(8)));
typedef unsigned short u16x8 __attribute__((ext_vector_type(8)));
typedef float f32x4 __attribute__((ext_vector_type(4)));

__device__ __forceinline__ float b2f(u16 u) {
    union { unsigned int i; float f; } v; v.i = ((unsigned int)u) << 16; return v.f;
}
__device__ __forceinline__ u16 f2b(float f) {
    union { unsigned int i; float f; } v; v.f = f;
    unsigned int r = (v.i + 0x7fff + ((v.i >> 16) & 1)) >> 16;
    return (u16)r;
}

// flag: 0 = inputs are bf16, 1 = inputs are fp32 (detected from x's raw bits)
__global__ void detect_k(const unsigned int* __restrict__ xw, int* __restrict__ flag)
{
    int tid = threadIdx.x;
    int cnt = 0;
#pragma unroll
    for (int i = 0; i < 4; ++i) {
        unsigned int w = xw[tid * 4 + i];
        unsigned int e = (w >> 7) & 0xFF;
        if (e >= 0x70 && e <= 0x87) cnt++;
    }
#pragma unroll
    for (int off = 32; off; off >>= 1) cnt += __shfl_down(cnt, off);
    if (tid == 0) flag[0] = (cnt > 128) ? 0 : 1;
}

// ---------------------------------------------------------------------------
// Fused relayout+convert for all 11 input tensors in ONE launch.
// Tensor ti, chunk y, vec4-index ii:
//   dst4[y*strideV + offV + ii] = cvt(src4[y*perV + ii])
// ---------------------------------------------------------------------------
struct CvtDesc { const void* src; u16* dst; long perV, strideV, offV; };
struct CvtPack { CvtDesc d[11]; long tot[12]; };

__global__ void cvt_all_k(CvtPack p, const int* __restrict__ flag)
{
    const int f = flag[0];
    const long total = p.tot[11];
    long i = (long)blockIdx.x * 256 + threadIdx.x;
    const long stride = (long)gridDim.x * 256;
    for (; i < total; i += stride) {
        int ti = 0;
#pragma unroll
        for (int t = 1; t < 11; ++t) if (i >= p.tot[t]) ti = t;
        const long loc = i - p.tot[ti];
        const long perV = p.d[ti].perV;
        long y  = loc / perV;
        long ii = loc - y * perV;
        long dj = y * p.d[ti].strideV + p.d[ti].offV + ii;
        ushort4 o;
        if (f) {
            float4 v = ((const float4*)p.d[ti].src)[loc];
            o.x = f2b(v.x); o.y = f2b(v.y); o.z = f2b(v.z); o.w = f2b(v.w);
        } else {
            o = ((const ushort4*)p.d[ti].src)[loc];
        }
        ((ushort4*)p.d[ti].dst)[dj] = o;
    }
}

// ---------------------------------------------------------------------------
// GEMM: C[m,n] = sum_k A[m,k] * B[n,k]   (A: MxK lda, B: NxK ldb)
// MODE 0: write bf16 to Cb; ropeMode: RoPE in epilogue for cols < 2048
//         (q|k of the fused qkv GEMM) using table rt.
// MODE 1: z = K-slice (kSplit slices); slices 0..kSplit-2 store fp32 partials
//         to Pf[z*M*ldc + off]; slice kSplit-1 does non-atomic Cf[off] += acc.
// M % 128 == 0, N % 128 == 0; K (or K/kSplit) % 32 == 0.
// Bijective XCD swizzle (m204). 1-deep prefetch double-buffer (T3-minimum):
// stage(j+1) issued before compute(j); single barrier per K-step.
// ---------------------------------------------------------------------------
template<int MODE>
__global__ __launch_bounds__(256, 2)
void gemm_bt(const u16* __restrict__ A, const u16* __restrict__ Bm,
             u16* __restrict__ Cb, float* __restrict__ Cf,
             float* __restrict__ Pf,
             int M, int N, int K, int lda, int ldb, int ldc,
             int kSplit, int ropeMode, const float2* __restrict__ rt)
{
    __shared__ __align__(16) u16 tA[2][128 * 32];
    __shared__ __align__(16) u16 tB[2][128 * 32];

    // --- XCD-aware bijective remap of the linear workgroup id ---
    const unsigned nx = gridDim.x, ny = gridDim.y;
    const unsigned nwg = nx * ny * gridDim.z;
    const unsigned lin = blockIdx.x + nx * (blockIdx.y + ny * blockIdx.z);
    const unsigned qd = nwg >> 3, rm = nwg & 7;
    const unsigned xcd = lin & 7, pos = lin >> 3;
    const unsigned wg = (xcd < rm ? xcd * (qd + 1)
                                  : rm * (qd + 1) + (xcd - rm) * qd) + pos;
    const unsigned bx = wg % nx;
    const unsigned tmp = wg / nx;
    const unsigned by = tmp % ny;
    const unsigned bz = tmp / ny;

    const int z = (int)bz;
    int kBeg = 0, kEnd = K;
    if (MODE == 1) {
        int ks = K / kSplit;
        kBeg = z * ks; kEnd = kBeg + ks;
    }

    const int row0 = by * 128;
    const int col0 = bx * 128;

    const int tid  = threadIdx.x;
    const int lane = tid & 63;
    const int wave = tid >> 6;
    const int wr = wave >> 1, wc = wave & 1;   // 2x2 waves of 64x64
    const int lrow = lane & 15;
    const int kg   = lane >> 4;

    f32x4 acc[4][4] = {};

    auto stage = [&](int bb, int k0) {
#pragma unroll
        for (int i = 0; i < 2; ++i) {          // A tile: 512 x 16B chunks
            int chunk = i * 256 + tid;
            int r = chunk >> 2, cg = chunk & 3;
            const u16* ga = A + (long)(row0 + r) * lda + (k0 + cg * 8);
            u16* la = tA[bb] + (size_t)(i * 256 + wave * 64) * 8;  // wave-uniform
            __builtin_amdgcn_global_load_lds(
                (const __attribute__((address_space(1))) void*)ga,
                (__attribute__((address_space(3))) void*)la, 16, 0, 0);
        }
#pragma unroll
        for (int i = 0; i < 2; ++i) {          // B tile
            int chunk = i * 256 + tid;
            int r = chunk >> 2, cg = chunk & 3;
            const u16* gb = Bm + (long)(col0 + r) * ldb + (k0 + cg * 8);
            u16* lb = tB[bb] + (size_t)(i * 256 + wave * 64) * 8;
            __builtin_amdgcn_global_load_lds(
                (const __attribute__((address_space(1))) void*)gb,
                (__attribute__((address_space(3))) void*)lb, 16, 0, 0);
        }
    };

    stage(0, kBeg);
    int cur = 0;

    for (int k0 = kBeg; k0 < kEnd; k0 += 32) {
        __syncthreads();                 // buf[cur] staged (vmcnt drained);
                                         // prior reads of buf[cur^1] done
        if (k0 + 32 < kEnd) stage(cur ^ 1, k0 + 32);   // prefetch overlaps

        const u16* pA_ = tA[cur];
        const u16* pB_ = tB[cur];
        bf16x8 af[4], bfr[4];
#pragma unroll
        for (int ti = 0; ti < 4; ++ti)
            af[ti] = *(const bf16x8*)&pA_[(wr * 64 + ti * 16 + lrow) * 32 + kg * 8];
#pragma unroll
        for (int tj = 0; tj < 4; ++tj)
            bfr[tj] = *(const bf16x8*)&pB_[(wc * 64 + tj * 16 + lrow) * 32 + kg * 8];
#pragma unroll
        for (int ti = 0; ti < 4; ++ti)
#pragma unroll
            for (int tj = 0; tj < 4; ++tj)
                acc[ti][tj] = __builtin_amdgcn_mfma_f32_16x16x32_bf16(
                    af[ti], bfr[tj], acc[ti][tj], 0, 0, 0);
        cur ^= 1;
    }

    // Epilogue: D[row = kg*4 + r][col = lane&15] per 16x16 tile.
    const int rbase = row0 + wr * 64;
    const int cbase = col0 + wc * 64 + lrow;

    if (MODE == 0) {
        const bool doRope = ropeMode && (cbase < 2048);  // q|k cols of qkv
#pragma unroll
        for (int ti = 0; ti < 4; ++ti) {
#pragma unroll
            for (int r = 0; r < 4; ++r) {
                int row = rbase + ti * 16 + kg * 4 + r;
                float o0 = acc[ti][0][r], o1 = acc[ti][1][r];
                float o2 = acc[ti][2][r], o3 = acc[ti][3][r];
                if (doRope) {
                    int t = row & 1023;
                    float2 c0 = rt[t * 32 + lrow];         // i = lrow
                    float2 c1 = rt[t * 32 + 16 + lrow];    // i = 16 + lrow
                    float n0 = o0 * c0.x - o2 * c0.y;
                    float n2 = o2 * c0.x + o0 * c0.y;
                    float n1 = o1 * c1.x - o3 * c1.y;
                    float n3 = o3 * c1.x + o1 * c1.y;
                    o0 = n0; o1 = n1; o2 = n2; o3 = n3;
                }
                float ov[4] = { o0, o1, o2, o3 };
#pragma unroll
                for (int tj = 0; tj < 4; ++tj)
                    Cb[(long)row * ldc + cbase + tj * 16] = f2b(ov[tj]);
            }
        }
    } else {
        const size_t pstr = (size_t)M * ldc;
        const bool last = (z == kSplit - 1);
#pragma unroll
        for (int ti = 0; ti < 4; ++ti) {
#pragma unroll
            for (int r = 0; r < 4; ++r) {
                int row = rbase + ti * 16 + kg * 4 + r;
#pragma unroll
                for (int tj = 0; tj < 4; ++tj) {
                    long off = (long)row * ldc + cbase + tj * 16;
                    if (last) Cf[off] += acc[ti][tj][r];   // single writer/cell
                    else      Pf[(size_t)z * pstr + off] = acc[ti][tj][r];
                }
            }
        }
    }
}

// ---------------------------------------------------------------------------
// Fused causal flash attention. One block = (b, head, 64 q-rows), 4 waves x
// 16 q-rows. K/V tiles double-buffered in LDS via global_load_lds with
// pre-swizzled global source; prefetch of tile j+1 overlaps compute of j.
// Longest q-tiles are dispatched first (qt = 15 - pos) to trim the tail.
// ---------------------------------------------------------------------------
__global__ __launch_bounds__(256, 2)
void flash_k(const u16* __restrict__ qkv, const u16* __restrict__ vt,
             u16* __restrict__ y)
{
    __shared__ __align__(16) u16 tK[2][64 * 64];
    __shared__ __align__(16) u16 tV[2][64 * 64];
    __shared__ __align__(16) u16 tP[4][16 * 64];

    const int bid0 = blockIdx.x;
    const int bid  = (bid0 & 7) * 64 + (bid0 >> 3);   // XCD swizzle (512%8==0)
    const int qt = 15 - (bid & 15);                   // longest first
    const int hh = (bid >> 4) & 15;
    const int b  = bid >> 8;

    const int tid  = threadIdx.x;
    const int lane = tid & 63;
    const int w    = tid >> 6;           // wave 0..3
    const int l15  = lane & 15;
    const int kg   = lane >> 4;          // 0..3

    const int wq0 = qt * 64 + w * 16;    // wave's first q row
    u16* tPw = tP[w];

    bf16x8 qf[2];
#pragma unroll
    for (int dk = 0; dk < 2; ++dk)
        qf[dk] = *(const bf16x8*)(qkv
            + (size_t)(b * 1024 + wq0 + l15) * 3072 + hh * 64 + dk * 32 + kg * 8);

    f32x4 acc_o[4] = {};
    float mrun = -3e38f;
    float lrun = 0.f;

    const u16* Kg0 = qkv + (size_t)(b * 1024) * 3072 + 1024 + hh * 64;
    const u16* Vg0 = vt + (size_t)((b * 16 + hh) * 64) * 1024;

    auto stage = [&](int bb, int j) {
#pragma unroll
        for (int i = 0; i < 2; ++i) {
            int chunk = i * 256 + tid;   // granule id 0..511
            int row = chunk >> 3, gc = chunk & 7;
            int sgc = gc ^ (row & 7);
            const u16* ga = Kg0 + (size_t)(j * 64 + row) * 3072 + sgc * 8;
            u16* la = tK[bb] + (size_t)(i * 256 + w * 64) * 8;  // wave-uniform
            __builtin_amdgcn_global_load_lds(
                (const __attribute__((address_space(1))) void*)ga,
                (__attribute__((address_space(3))) void*)la, 16, 0, 0);
            const u16* gb = Vg0 + (size_t)row * 1024 + j * 64 + sgc * 8;
            u16* lb = tV[bb] + (size_t)(i * 256 + w * 64) * 8;
            __builtin_amdgcn_global_load_lds(
                (const __attribute__((address_space(1))) void*)gb,
                (__attribute__((address_space(3))) void*)lb, 16, 0, 0);
        }
    };

    stage(0, 0);
    int cur = 0;

    for (int j = 0; j <= qt; ++j) {
        __syncthreads();
        if (j < qt) stage(cur ^ 1, j + 1);   // prefetch overlaps compute

        const u16* K_ = tK[cur];
        const u16* V_ = tV[cur];

        f32x4 s[4] = {};
#pragma unroll
        for (int dk = 0; dk < 2; ++dk) {
            bf16x8 ak[4];
#pragma unroll
            for (int kvt = 0; kvt < 4; ++kvt) {
                int row = kvt * 16 + l15;
                int g = (dk * 4 + kg) ^ (row & 7);
                ak[kvt] = *(const bf16x8*)&K_[row * 64 + g * 8];
            }
#pragma unroll
            for (int kvt = 0; kvt < 4; ++kvt)
                s[kvt] = __builtin_amdgcn_mfma_f32_16x16x32_bf16(
                    ak[kvt], qf[dk], s[kvt], 0, 0, 0);
        }

        float tmax = -3e38f;
        const bool maskt = (j == qt);
#pragma unroll
        for (int kvt = 0; kvt < 4; ++kvt) {
            f32x4 v = s[kvt];
#pragma unroll
            for (int r = 0; r < 4; ++r) {
                float sv = v[r] * 0.125f;
                if (maskt && (j * 64 + kvt * 16 + kg * 4 + r > wq0 + l15))
                    sv = -3e38f;
                v[r] = sv;
                tmax = fmaxf(tmax, sv);
            }
            s[kvt] = v;
        }
        tmax = fmaxf(tmax, __shfl_xor(tmax, 16));
        tmax = fmaxf(tmax, __shfl_xor(tmax, 32));

        const float mn = fmaxf(mrun, tmax);
        const float sf = __expf(mrun - mn);
        mrun = mn;

#pragma unroll
        for (int ro = 0; ro < 4; ++ro) {
            float f = __shfl(sf, kg * 4 + ro);
#pragma unroll
            for (int dj = 0; dj < 4; ++dj)
                acc_o[dj][ro] *= f;
        }

        float tsum = 0.f;
#pragma unroll
        for (int kvt = 0; kvt < 4; ++kvt) {
            f32x4 v = s[kvt];
            float p0 = __expf(v[0] - mn);
            float p1 = __expf(v[1] - mn);
            float p2 = __expf(v[2] - mn);
            float p3 = __expf(v[3] - mn);
            tsum += p0 + p1 + p2 + p3;
            ushort4 pk;
            pk.x = f2b(p0); pk.y = f2b(p1); pk.z = f2b(p2); pk.w = f2b(p3);
            int g = (kvt * 2 + (kg >> 1)) ^ (l15 & 7);
            *(ushort4*)&tPw[l15 * 64 + g * 8 + (kg & 1) * 4] = pk;
        }
        tsum += __shfl_xor(tsum, 16);
        tsum += __shfl_xor(tsum, 32);
        lrun = lrun * sf + tsum;

#pragma unroll
        for (int ki = 0; ki < 2; ++ki) {
            bf16x8 ap, bv[4];
            {
                int g = (ki * 4 + kg) ^ (l15 & 7);
                ap = *(const bf16x8*)&tPw[l15 * 64 + g * 8];
            }
#pragma unroll
            for (int dj = 0; dj < 4; ++dj) {
                int row = dj * 16 + l15;
                int g = (ki * 4 + kg) ^ (row & 7);
                bv[dj] = *(const bf16x8*)&V_[row * 64 + g * 8];
            }
#pragma unroll
            for (int dj = 0; dj < 4; ++dj)
                acc_o[dj] = __builtin_amdgcn_mfma_f32_16x16x32_bf16(
                    ap, bv[dj], acc_o[dj], 0, 0, 0);
        }
        cur ^= 1;
    }

    const float inv = 1.0f / lrun;
#pragma unroll
    for (int ro = 0; ro < 4; ++ro) {
        float iv = __shfl(inv, kg * 4 + ro);
        size_t rowo = (size_t)(b * 1024 + wq0 + kg * 4 + ro) * 1024
                    + hh * 64 + l15;
#pragma unroll
        for (int dj = 0; dj < 4; ++dj)
            y[rowo + dj * 16] = f2b(acc_o[dj][ro] * iv);
    }
}

// h[bt,c] = sum_f x[bt,f] * w_in[c,f]   (K=9, fp32 out)
__global__ void input_proj_k(const u16* __restrict__ x, const u16* __restrict__ w,
                             float* __restrict__ h)
{
    int idx = blockIdx.x * 256 + threadIdx.x;      // 2M
    int bt = idx >> 10, c = idx & 1023;
    float s = 0.f;
#pragma unroll
    for (int f = 0; f < 9; ++f) s += b2f(x[bt * 9 + f]) * b2f(w[c * 9 + f]);
    h[idx] = s;
}

// Fused residual-reduce + RMSNorm.
// v = h[row] + sum_{p<nP} P[p][row];  if (hOut) hOut[row] = v;
// out[row] = v * rsqrt(mean(v^2)+eps) * g.   isFinal&&flag -> fp32 out.
__global__ void rms_k(const float* __restrict__ h, const float* __restrict__ P,
                      int nP, const u16* __restrict__ g,
                      void* __restrict__ out, float* __restrict__ hOut,
                      int isFinal, const int* __restrict__ flag)
{
    __shared__ float red[8];
    const int row = blockIdx.x;
    const int tid = threadIdx.x;
    float4 v = ((const float4*)(h + (size_t)row * C_))[tid];
    for (int p = 0; p < nP; ++p) {
        float4 pv = ((const float4*)P)[(size_t)p * 524288 + row * 256 + tid];
        v.x += pv.x; v.y += pv.y; v.z += pv.z; v.w += pv.w;
    }
    if (hOut) ((float4*)hOut)[(size_t)row * 256 + tid] = v;
    float ss = v.x * v.x + v.y * v.y + v.z * v.z + v.w * v.w;
#pragma unroll
    for (int off = 32; off; off >>= 1) ss += __shfl_down(ss, off);
    int lane = tid & 63, wave = tid >> 6;
    if (lane == 0) red[wave] = ss;
    __syncthreads();
    if (tid == 0)
        red[4] = rsqrtf((red[0] + red[1] + red[2] + red[3]) / (float)C_ + EPS_);
    __syncthreads();
    const float r = red[4];
    ushort4 gv = ((const ushort4*)g)[tid];
    float o0 = v.x * r * b2f(gv.x);
    float o1 = v.y * r * b2f(gv.y);
    float o2 = v.z * r * b2f(gv.z);
    float o3 = v.w * r * b2f(gv.w);
    if (isFinal && flag[0]) {
        ((float4*)out)[(size_t)row * 256 + tid] = make_float4(o0, o1, o2, o3);
    } else {
        ushort4 o; o.x = f2b(o0); o.y = f2b(o1); o.z = f2b(o2); o.w = f2b(o3);
        ((ushort4*)out)[(size_t)row * 256 + tid] = o;
    }
}

// cos/sin table: tab[t*32+i] = {cos,sin}(t * 10000^(-i/32)), t<1024, i<32
__global__ void rope_tab_k(float2* __restrict__ tab)
{
    int idx = blockIdx.x * 256 + threadIdx.x;      // 32768
    int i = idx & 31;
    int t = idx >> 5;
    float invf = powf(10000.0f, -(float)i / 32.0f);
    float fr = (float)t * invf;
    tab[idx] = make_float2(cosf(fr), sinf(fr));
}

// vt[b,h,d,s] = qkv[b,s, 2048 + h*64 + d]  — LDS-tiled 64x64 transpose.
__global__ void vtrans_k(const u16* __restrict__ qkv, u16* __restrict__ vt)
{
    __shared__ u16 tile[64][68];                   // pad 4 u16
    const int bz = blockIdx.x;                     // 512 = 2b * 16h * 16s-tiles
    const int s0 = (bz & 15) << 6;
    const int hh = (bz >> 4) & 15;
    const int b  = bz >> 8;
    const int tid = threadIdx.x;
#pragma unroll
    for (int it = 0; it < 2; ++it) {
        int id = it * 256 + tid;                   // 0..511
        int r  = id >> 3;                          // s-row within tile
        int cg = id & 7;                           // 8-wide d chunk
        const u16* src = qkv + (size_t)(b * 1024 + s0 + r) * 3072
                             + 2048 + hh * 64 + cg * 8;
        ushort4 a0 = *(const ushort4*)src;
        ushort4 a1 = *(const ushort4*)(src + 4);
        *(ushort4*)&tile[r][cg * 8]     = a0;
        *(ushort4*)&tile[r][cg * 8 + 4] = a1;
    }
    __syncthreads();
#pragma unroll
    for (int it = 0; it < 2; ++it) {
        int id = it * 256 + tid;
        int d  = id >> 3;                          // d row of output
        int cg = id & 7;                           // 8-wide s chunk
        ushort4 o0, o1;
        o0.x = tile[cg * 8 + 0][d]; o0.y = tile[cg * 8 + 1][d];
        o0.z = tile[cg * 8 + 2][d]; o0.w = tile[cg * 8 + 3][d];
        o1.x = tile[cg * 8 + 4][d]; o1.y = tile[cg * 8 + 5][d];
        o1.z = tile[cg * 8 + 6][d]; o1.w = tile[cg * 8 + 7][d];
        u16* dst = vt + (size_t)((b * 16 + hh) * 64 + d) * 1024 + s0 + cg * 8;
        *(ushort4*)dst       = o0;
        *(ushort4*)(dst + 4) = o1;
    }
}

// u12[m][c] = silu(u12[m][c]) * u12[m][c+2816]   (c < 2816), ushort8
__global__ void silu_mul_k(u16* __restrict__ u12)
{
    int idx = blockIdx.x * 256 + threadIdx.x;      // 2048*352 = 720896
    int m = idx / 352;
    int c = idx - m * 352;
    u16* row = u12 + (size_t)m * 5632;
    u16x8 a8 = *(const u16x8*)(row + c * 8);
    u16x8 b8 = *(const u16x8*)(row + 2816 + c * 8);
    u16x8 o;
#pragma unroll
    for (int j = 0; j < 8; ++j) {
        float a = b2f(a8[j]);
        float m2 = a / (1.f + __expf(-a));
        o[j] = f2b(m2 * b2f(b8[j]));
    }
    *(u16x8*)(row + c * 8) = o;
}

// ---------------------------------------------------------------------------
static inline void launch_gemm(bool add, const u16* A, const u16* Bm, void* C,
                               float* Pf,
                               int M, int N, int K, int lda, int ldb, int ldc,
                               int kSplit, int ropeMode, const float2* rt,
                               hipStream_t stream)
{
    dim3 g(N / 128, M / 128, add ? kSplit : 1);
    if (add)
        gemm_bt<1><<<g, 256, 0, stream>>>(A, Bm, nullptr, (float*)C, Pf,
            M, N, K, lda, ldb, ldc, kSplit, 0, nullptr);
    else
        gemm_bt<0><<<g, 256, 0, stream>>>(A, Bm, (u16*)C, nullptr, nullptr,
            M, N, K, lda, ldb, ldc, 1, ropeMode, rt);
}

extern "C" void kernel_launch(void* const* d_in, const int* in_sizes, int n_in,
                              void* d_out, int out_size, void* d_ws, size_t ws_size,
                              hipStream_t stream)
{
    char* w = (char*)d_ws;
    // Layout:
    //   [0,8)    h fp32 residual
    //   [8,32)   P: 3 fp32 split-K partial slices (8 MB each); overlaps
    //            qkv [12,24) and vt [24,28) (disjoint lifetimes)
    //   [32,54)  u12 MLP buffer [2048][5632] bf16
    //   [56,60)  y attention output
    //   [60,64)  a (rms output, bf16)
    float* h   = (float*)w;
    float* P   = (float*)(w + (8u  << 20));
    u16* qkv   = (u16*)(w + (12u << 20));
    u16* vt    = (u16*)(w + (24u << 20));
    u16* u12   = (u16*)(w + (32u << 20));
    u16* y     = (u16*)(w + (56u << 20));
    u16* a     = (u16*)(w + (60u << 20));

    size_t off = (size_t)64 << 20;
    u16* cx    = (u16*)(w + off); off += ((size_t)B_*T_*9*2   + 255) & ~(size_t)255;
    u16* cwin  = (u16*)(w + off); off += ((size_t)C_*9*2      + 255) & ~(size_t)255;
    u16* cwqkv = (u16*)(w + off); off += (size_t)L_*3072*1024*2;   // fused q|k|v
    u16* cwo   = (u16*)(w + off); off += (size_t)L_*C_*C_*2;
    u16* cw12  = (u16*)(w + off); off += (size_t)L_*2*HFF_*C_*2;   // fused w1|w2
    u16* cw3   = (u16*)(w + off); off += (size_t)L_*C_*HFF_*2;
    u16* cg1   = (u16*)(w + off); off += ((size_t)L_*C_*2 + 255) & ~(size_t)255;
    u16* cg2   = (u16*)(w + off); off += ((size_t)L_*C_*2 + 255) & ~(size_t)255;
    u16* cgf   = (u16*)(w + off); off += ((size_t)C_*2    + 255) & ~(size_t)255;
    int* flag  = (int*)(w + off); off += 256;
    float2* rtab = (float2*)(w + off);               // 1024*32*8 = 256 KB

    detect_k<<<1, 64, 0, stream>>>((const unsigned int*)d_in[0], flag);

    // --- fused weight conversion (single launch) ---
    const long CCv  = (long)C_ * C_ / 4;        // 262144
    const long HCv  = (long)HFF_ * C_ / 4;      // 720896
    CvtPack cp;
    auto setd = [&](int i, const void* s, u16* d, long perV, long strV, long offV,
                    int chunks) {
        cp.d[i] = { s, d, perV, strV, offV };
        cp.tot[i + 1] = cp.tot[i] + perV * chunks;
    };
    cp.tot[0] = 0;
    setd(0,  d_in[0],  cx,    (long)B_*T_*9/4, 0,     0,   1);
    setd(1,  d_in[1],  cwin,  (long)C_*9/4,    0,     0,   1);
    setd(2,  d_in[2],  cwqkv, CCv,             3*CCv, 0,   L_);   // wq
    setd(3,  d_in[3],  cwqkv, 2*CCv,           3*CCv, CCv, L_);   // wkv
    setd(4,  d_in[4],  cwo,   CCv,             CCv,   0,   L_);
    setd(5,  d_in[5],  cw12,  HCv,             2*HCv, 0,   L_);   // w1
    setd(6,  d_in[6],  cw12,  HCv,             2*HCv, HCv, L_);   // w2
    setd(7,  d_in[7],  cw3,   HCv,             HCv,   0,   L_);
    setd(8,  d_in[8],  cg1,   (long)L_*C_/4,   0,     0,   1);
    setd(9,  d_in[9],  cg2,   (long)L_*C_/4,   0,     0,   1);
    setd(10, d_in[10], cgf,   (long)C_/4,      0,     0,   1);
    cvt_all_k<<<4096, 256, 0, stream>>>(cp, flag);

    rope_tab_k<<<128, 256, 0, stream>>>(rtab);

    input_proj_k<<<8192, 256, 0, stream>>>(cx, cwin, h);

    for (int l = 0; l < L_; ++l) {
        const u16* wqkv_l = cwqkv + (size_t)l * 3072 * 1024;
        const u16* wo_l   = cwo   + (size_t)l * C_ * C_;
        const u16* w12_l  = cw12  + (size_t)l * 2 * HFF_ * C_;
        const u16* w3_l   = cw3   + (size_t)l * C_ * HFF_;

        // --- attention ---
        if (l == 0)
            rms_k<<<2048, 256, 0, stream>>>(h, nullptr, 0, cg1, a, nullptr, 0, flag);
        else
            rms_k<<<2048, 256, 0, stream>>>(h, P, 3, cg1 + l * C_, a, h, 0, flag);
        // qkv[2048][3072] = a @ [wq|wk|wv]^T  (single N=3072 GEMM; RoPE fused)
        launch_gemm(false, a, wqkv_l, qkv, nullptr,
                    2048, 3072, 1024, 1024, 1024, 3072, 1, 1, rtab, stream);
        vtrans_k<<<512, 256, 0, stream>>>(qkv, vt);
        flash_k<<<512, 256, 0, stream>>>(qkv, vt, y);
        // wo split-K x4: slices 0-2 -> P, slice 3 RMW h += acc
        launch_gemm(true, y, wo_l, h, P, 2048, 1024, 1024, 1024, 1024, 1024,
                    4, 0, nullptr, stream);

        // --- MLP ---
        rms_k<<<2048, 256, 0, stream>>>(h, P, 3, cg2 + l * C_, a, h, 0, flag);
        // u12[2048][5632] = a @ [w1|w2]^T   (single N=5632 GEMM)
        launch_gemm(false, a, w12_l, u12, nullptr,
                    2048, 5632, 1024, 1024, 1024, 5632, 1, 0, nullptr, stream);
        silu_mul_k<<<2816, 256, 0, stream>>>(u12);
        // w3 split-K x4 (K=2816 -> 704/slice): slices 0-2 -> P, slice 3 RMW h
        // NOTE: lda=5632 (interleaved u12), ldb=2816 (w3 is [1024][2816]).
        launch_gemm(true, u12, w3_l, h, P, 2048, 1024, 2816, 5632, 2816, 1024,
                    4, 0, nullptr, stream);
    }

    rms_k<<<2048, 256, 0, stream>>>(h, P, 3, cgf, d_out, nullptr, 1, flag);
}